// Round 7
// baseline (2273.839 us; speedup 1.0000x reference)
//
#include <hip/hip_runtime.h>
#include <hip/hip_bf16.h>

// Problem constants (match reference)
#define NN 100000
#define EE 1600000
#define CC 8
#define HH 64
#define NF 140
#define CF 18
#define BB 16
#define NROWS (NN * CC)          // 800000 rows of [64]
#define ALPHA 0.2f

// R15: fp8 gather + SINGLE bf16 buffer (in-place layers).
// R14 showed ws_size < 269MB (guard tripped, bf16 fallback ran). Fix is
// structural: all cross-node coupling goes through the gather operand, and
// the p-path/MFMA bf16 reads are row-local to the owning wave. So with the
// gather redirected to an fp8 snapshot G, each layer can run IN-PLACE on one
// bf16 buffer Y (wave reads its own 16 rows, then overwrites them).
// hd0 emits the layer-0 gather operand (x0@Wd0) directly as fp8 into G.
// Footprint: Y 102.4 + G 51.2 + col 12.8 + setup 27 + misc ~= 193MB.
// fp8 theory (R9/R10): gathers are byte-throughput-bound; fp8 node row =
// 512B, one 64-lane x 16B instruction covers TWO edges (half-wave each).
// Demand bytes halve. Dense/MFMA/residual/pool all stay bf16/f32.
// KEPT: chunked place_k (R11/R12).
// Flow: hd0 -> G(fp8),Y(bf16) ; l0: gather G, Y in-place ; conv Y->G ;
// spmm1: gather G, Y in-place ; conv Y->G ; spmm2: in-place ; pool(Y).

typedef unsigned short u16;
typedef unsigned int u32;
typedef unsigned char u8;
typedef __attribute__((ext_vector_type(8))) short short8;   // 8 bf16 (4 VGPRs)
typedef __attribute__((ext_vector_type(4))) float f32x4;    // MFMA accum
typedef __attribute__((ext_vector_type(4))) float fv4;
typedef __attribute__((ext_vector_type(2))) float f32x2;

__device__ __forceinline__ float rdlane(float v, int l) {
    return __int_as_float(__builtin_amdgcn_readlane(__float_as_int(v), l));
}
__device__ __forceinline__ float lrelu(float x) { return x > 0.f ? x : ALPHA * x; }
__device__ __forceinline__ float wave_sum64(float v) {
#pragma unroll
    for (int m = 1; m < 64; m <<= 1) v += __shfl_xor(v, m, 64);
    return v;
}
__device__ __forceinline__ float b2f(u16 u) { return __uint_as_float(((u32)u) << 16); }
__device__ __forceinline__ u32 f2b(float f) {
    u32 u = __float_as_uint(f);
    return (u + 0x7fffu + ((u >> 16) & 1u)) >> 16;
}
__device__ __forceinline__ u32 pack2(float lo, float hi) {
    return f2b(lo) | (f2b(hi) << 16);
}
__device__ __forceinline__ short8 ld_frag(const u16* p) {
    union { uint4 u; short8 s; } c;
    c.u = *(const uint4*)p;
    return c.s;
}

// ---------------- fp8 e4m3 helpers ----------------
#if __has_builtin(__builtin_amdgcn_cvt_pk_f32_fp8) && __has_builtin(__builtin_amdgcn_cvt_pk_fp8_f32)
#define HAS_HW_FP8 1
#else
#define HAS_HW_FP8 0
#endif

__device__ __forceinline__ float dec8_sw(u32 b) {
    u32 u = ((b & 0x80u) << 24) | ((b & 0x7fu) << 20);
    return __uint_as_float(u) * 0x1.0p+120f;
}
__device__ __forceinline__ u32 enc8_sw(float f) {
    f = fminf(fmaxf(f, -448.f), 448.f);
    u32 u = __float_as_uint(f * 0x1.0p-120f);
    u32 r = u + 0x7ffffu + ((u >> 20) & 1u);
    return ((r >> 24) & 0x80u) | ((r >> 20) & 0x7fu);
}
__device__ __forceinline__ u32 pk4_fp8(float a, float b, float c, float d) {
#if HAS_HW_FP8
    u32 w = 0;
    w = __builtin_amdgcn_cvt_pk_fp8_f32(a, b, w, false);
    w = __builtin_amdgcn_cvt_pk_fp8_f32(c, d, w, true);
    return w;
#else
    return enc8_sw(a) | (enc8_sw(b) << 8) | (enc8_sw(c) << 16) | (enc8_sw(d) << 24);
#endif
}
// accumulate 16 fp8 values (one uint4) into a[16]
__device__ __forceinline__ void accf8(float* a, uint4 t) {
#if HAS_HW_FP8
    f32x2 d;
    d = __builtin_amdgcn_cvt_pk_f32_fp8(t.x, false); a[0] += d.x;  a[1] += d.y;
    d = __builtin_amdgcn_cvt_pk_f32_fp8(t.x, true);  a[2] += d.x;  a[3] += d.y;
    d = __builtin_amdgcn_cvt_pk_f32_fp8(t.y, false); a[4] += d.x;  a[5] += d.y;
    d = __builtin_amdgcn_cvt_pk_f32_fp8(t.y, true);  a[6] += d.x;  a[7] += d.y;
    d = __builtin_amdgcn_cvt_pk_f32_fp8(t.z, false); a[8] += d.x;  a[9] += d.y;
    d = __builtin_amdgcn_cvt_pk_f32_fp8(t.z, true);  a[10] += d.x; a[11] += d.y;
    d = __builtin_amdgcn_cvt_pk_f32_fp8(t.w, false); a[12] += d.x; a[13] += d.y;
    d = __builtin_amdgcn_cvt_pk_f32_fp8(t.w, true);  a[14] += d.x; a[15] += d.y;
#else
    u32 w[4] = {t.x, t.y, t.z, t.w};
#pragma unroll
    for (int q = 0; q < 4; q++) {
        a[q*4+0] += dec8_sw(w[q] & 0xffu);
        a[q*4+1] += dec8_sw((w[q] >> 8) & 0xffu);
        a[q*4+2] += dec8_sw((w[q] >> 16) & 0xffu);
        a[q*4+3] += dec8_sw((w[q] >> 24) & 0xffu);
    }
#endif
}

// ---------------- CSR build ----------------
__global__ __launch_bounds__(256) void deg_count_k(const int* __restrict__ src,
                                                   const int* __restrict__ dst,
                                                   int* __restrict__ deg) {
    int e = blockIdx.x * 256 + threadIdx.x;
    if (e < EE) atomicAdd(&deg[dst[e]], 1);
    else if (e < 2 * EE) atomicAdd(&deg[src[e - EE]], 1);
}

__global__ __launch_bounds__(1024) void scan1_k(const int* __restrict__ deg,
                                                int* __restrict__ row_ptr,
                                                int* __restrict__ bsum, int n) {
    __shared__ int lds[17];
    int i = blockIdx.x * 1024 + threadIdx.x;
    int lane = threadIdx.x & 63, wv = threadIdx.x >> 6;
    int val = (i < n) ? deg[i] : 0;
    int v = val;
#pragma unroll
    for (int d = 1; d < 64; d <<= 1) {
        int t = __shfl_up(v, d, 64);
        if (lane >= d) v += t;
    }
    if (lane == 63) lds[wv] = v;
    __syncthreads();
    if (threadIdx.x == 0) {
        int run = 0;
#pragma unroll
        for (int k = 0; k < 16; k++) { int t = lds[k]; lds[k] = run; run += t; }
        lds[16] = run;
    }
    __syncthreads();
    if (i < n) row_ptr[i] = v - val + lds[wv];
    if (threadIdx.x == 1023) bsum[blockIdx.x] = lds[16];
}

__global__ void scan2_k(int* __restrict__ bsum, int nb) {
    int run = 0;
    for (int b = 0; b < nb; b++) { int t = bsum[b]; bsum[b] = run; run += t; }
    bsum[nb] = run;
}

__global__ __launch_bounds__(1024) void scan3_k(int* __restrict__ row_ptr,
                                                int* __restrict__ cursor,
                                                const int* __restrict__ bsum,
                                                int n, int nb) {
    int i = blockIdx.x * 1024 + threadIdx.x;
    if (i < n) {
        int v = row_ptr[i] + bsum[blockIdx.x];
        row_ptr[i] = v;
        cursor[i] = v;
    }
    if (i == 0) row_ptr[n] = bsum[nb];
}

// Chunked placement (R11): only edges whose dst node is in [c0,c1).
__global__ __launch_bounds__(256) void place_k(const int* __restrict__ src,
                                               const int* __restrict__ dst,
                                               int* __restrict__ cursor,
                                               int* __restrict__ col,
                                               int c0, int c1) {
    int e = blockIdx.x * 256 + threadIdx.x;
    int node, other;
    if (e < EE) { node = dst[e]; other = src[e]; }
    else if (e < 2 * EE) { node = src[e - EE]; other = dst[e - EE]; }
    else return;
    if (node < c0 || node >= c1) return;
    int pos = atomicAdd(&cursor[node], 1);
    col[pos] = other;
}

// ---------------- weight prep: transposed bf16 weights ----------------
__global__ __launch_bounds__(256) void prep_w_k(const float* __restrict__ Wd1, const float* __restrict__ Wp1,
                                                const float* __restrict__ Wd2, const float* __restrict__ Wp2,
                                                const float* __restrict__ Wd0nf, const float* __restrict__ Wp0nf,
                                                u16* __restrict__ WT) {
    int i = blockIdx.x * 256 + threadIdx.x;
    if (i < 4 * 4096) {
        int w = i >> 12, idx = i & 4095;
        int n = idx >> 6, k = idx & 63;
        const float* W = (w == 0) ? Wd1 : (w == 1) ? Wp1 : (w == 2) ? Wd2 : Wp2;
        WT[w * 4096 + n * 64 + k] = (u16)f2b(W[k * 64 + n]);
    } else {
        int j = i - 4 * 4096;
        if (j < 2 * 64 * 160) {
            int w = j / 10240, idx = j % 10240;
            int n = idx / 160, k = idx % 160;
            const float* W = w ? Wp0nf : Wd0nf;
            WT[16384 + w * 10240 + n * 160 + k] = (k < 140) ? (u16)f2b(W[k * 64 + n]) : (u16)0;
        }
    }
}

// op_d/op_p tables: [120][64] f32 = op_emb @ W_top (rows 0..63 of W_d0 / W_p0)
__global__ __launch_bounds__(256) void op_dp_k(const float* __restrict__ op_emb,
                                               const float* __restrict__ Wd_top,
                                               const float* __restrict__ Wp_top,
                                               float* __restrict__ op_d,
                                               float* __restrict__ op_p) {
    int lane = threadIdx.x & 63;
    int wid = (blockIdx.x * 256 + threadIdx.x) >> 6;
    if (wid >= 120) return;
    float v = op_emb[wid * 64 + lane];
    float ad = 0.f, ap = 0.f;
    for (int k = 0; k < 64; k++) {
        float s = rdlane(v, k);
        ad = fmaf(s, Wd_top[k * 64 + lane], ad);
        ap = fmaf(s, Wp_top[k * 64 + lane], ap);
    }
    op_d[wid * 64 + lane] = ad;
    op_p[wid * 64 + lane] = ap;
}

// ---------------- nf projections via MFMA ----------------
__global__ __launch_bounds__(256) void nf_mfma_k(const float* __restrict__ nf,
                                                 const u16* __restrict__ WdT0,
                                                 const u16* __restrict__ WpT0,
                                                 u16* __restrict__ nf_d,
                                                 u16* __restrict__ nf_p) {
    int lane = threadIdx.x & 63;
    int m = lane & 15, q = lane >> 4;
    int wid = (blockIdx.x * 256 + threadIdx.x) >> 6;
    int nw = (gridDim.x * 256) >> 6;
    for (int rb = wid; rb < NN / 16; rb += nw) {
        int node0 = rb * 16;
        const float* row = nf + (size_t)(node0 + m) * 140;
        short8 af[5];
#pragma unroll
        for (int s = 0; s < 5; s++) {
            int k0 = s * 32 + q * 8;
            float f[8];
            if (s < 4) {
                fv4 lo = __builtin_nontemporal_load((const fv4*)(row + k0));
                fv4 hi = __builtin_nontemporal_load((const fv4*)(row + k0 + 4));
                f[0]=lo.x; f[1]=lo.y; f[2]=lo.z; f[3]=lo.w;
                f[4]=hi.x; f[5]=hi.y; f[6]=hi.z; f[7]=hi.w;
            } else {
#pragma unroll
                for (int j = 0; j < 8; j++) f[j] = 0.f;
                if (q == 0) {
                    fv4 lo = __builtin_nontemporal_load((const fv4*)(row + 128));
                    fv4 hi = __builtin_nontemporal_load((const fv4*)(row + 132));
                    f[0]=lo.x; f[1]=lo.y; f[2]=lo.z; f[3]=lo.w;
                    f[4]=hi.x; f[5]=hi.y; f[6]=hi.z; f[7]=hi.w;
                } else if (q == 1) {
                    fv4 lo = __builtin_nontemporal_load((const fv4*)(row + 136));
                    f[0]=lo.x; f[1]=lo.y; f[2]=lo.z; f[3]=lo.w;
                }
            }
            short8 t;
#pragma unroll
            for (int j = 0; j < 8; j++) t[j] = (short)f2b(f[j]);
            af[s] = t;
        }
        f32x4 ad[4], ap[4];
#pragma unroll
        for (int t = 0; t < 4; t++) {
            ad[t] = (f32x4){0.f, 0.f, 0.f, 0.f};
            ap[t] = (f32x4){0.f, 0.f, 0.f, 0.f};
        }
#pragma unroll
        for (int s = 0; s < 5; s++) {
#pragma unroll
            for (int t = 0; t < 4; t++) {
                int boff = (t * 16 + m) * 160 + s * 32 + q * 8;
                short8 bdw = ld_frag(WdT0 + boff);
                short8 bpw = ld_frag(WpT0 + boff);
                ad[t] = __builtin_amdgcn_mfma_f32_16x16x32_bf16(af[s], bdw, ad[t], 0, 0, 0);
                ap[t] = __builtin_amdgcn_mfma_f32_16x16x32_bf16(af[s], bpw, ap[t], 0, 0, 0);
            }
        }
#pragma unroll
        for (int r = 0; r < 4; r++) {
            size_t nrow = (size_t)(node0 + q * 4 + r);
#pragma unroll
            for (int t = 0; t < 4; t++) {
                nf_d[nrow * 64 + t * 16 + m] = (u16)f2b(ad[t][r]);
                nf_p[nrow * 64 + t * 16 + m] = (u16)f2b(ap[t][r]);
            }
        }
    }
}

// hd0 v3: G[row] = fp8(op_d + nf_d + cf@WdBot) ; Y[row] = bf16(op_p + nf_p + cf@WpBot)
__global__ __launch_bounds__(256) void hd0_dual_k(u8* __restrict__ G,
                                                  u16* __restrict__ Y,
                                                  const float* __restrict__ cf,
                                                  const int* __restrict__ op_ids,
                                                  const u16* __restrict__ nf_d,
                                                  const u16* __restrict__ nf_p,
                                                  const float* __restrict__ op_d,
                                                  const float* __restrict__ op_p,
                                                  const float* __restrict__ WdBot,
                                                  const float* __restrict__ WpBot) {
    int lane = threadIdx.x & 63;
    float wbd[18], wbp[18];
#pragma unroll
    for (int k = 0; k < 18; k++) { wbd[k] = WdBot[k * 64 + lane]; wbp[k] = WpBot[k * 64 + lane]; }
    int wid = (blockIdx.x * 256 + threadIdx.x) >> 6;
    int nw = (gridDim.x * 256) >> 6;
    for (int row = wid; row < NROWS; row += nw) {
        int n = row >> 3;
        float cfv = (lane < 18) ? __builtin_nontemporal_load(cf + (size_t)row * 18 + lane) : 0.f;
        int op = op_ids[n];
        float accd = op_d[op * 64 + lane] + b2f(nf_d[(size_t)n * 64 + lane]);
        float accp = op_p[op * 64 + lane] + b2f(nf_p[(size_t)n * 64 + lane]);
#pragma unroll
        for (int k = 0; k < 18; k++) {
            float s = rdlane(cfv, k);
            accd = fmaf(s, wbd[k], accd);
            accp = fmaf(s, wbp[k], accp);
        }
        // pack 4 lanes' accd into one fp8 u32 (lane&3==0 writes)
        float f1 = __shfl_down(accd, 1, 64);
        float f2 = __shfl_down(accd, 2, 64);
        float f3 = __shfl_down(accd, 3, 64);
        if ((lane & 3) == 0)
            ((u32*)G)[(size_t)row * 16 + (lane >> 2)] = pk4_fp8(accd, f1, f2, f3);
        Y[(size_t)row * 64 + lane] = (u16)f2b(accp);
    }
}

// ---------------- bf16 -> fp8 mirror conversion ----------------
__global__ __launch_bounds__(256) void conv_fp8_k(const u16* __restrict__ src,
                                                  uint2* __restrict__ dst) {
    int i = blockIdx.x * 256 + threadIdx.x;   // each thread: 8 elems
    if (i >= NROWS * 64 / 8) return;
    short8 v = ld_frag(src + (size_t)i * 8);
    float f[8];
#pragma unroll
    for (int k = 0; k < 8; k++) f[k] = b2f((u16)v[k]);
    uint2 o;
    o.x = pk4_fp8(f[0], f[1], f[2], f[3]);
    o.y = pk4_fp8(f[4], f[5], f[6], f[7]);
    dst[i] = o;
}

// ---------------- FUSED layer 0: fp8 gather + combine, Y in-place ----------------
// One wave per node. Two edges per load: half h=lane>>5 picks the edge,
// sl=lane&31 picks 16B of the 512B fp8 node row (config sl>>2, feats
// (sl&3)*16..+15). Cross-half shfl reduce; lanes<32 do combine+l2norm+store.
__global__ __launch_bounds__(256) void fused_l0_f8_k(const u8* __restrict__ G,
                                                     u16* __restrict__ Y,
                                                     const int* __restrict__ row_ptr,
                                                     const int* __restrict__ col,
                                                     const float* __restrict__ bd,
                                                     const float* __restrict__ bp) {
    int wid = (blockIdx.x * 256 + threadIdx.x) >> 6;
    int lane = threadIdx.x & 63;
    if (wid >= NN) return;
    int h = lane >> 5, sl = lane & 31;
    int start = row_ptr[wid], end = row_ptr[wid + 1];
    float a[16];
#pragma unroll
    for (int k = 0; k < 16; k++) a[k] = 0.f;
    int j = start;
    for (; j + 16 <= end; j += 16) {
        uint4 t[8];
#pragma unroll
        for (int u = 0; u < 8; u++)
            t[u] = *(const uint4*)(G + (size_t)col[j + 2 * u + h] * 512 + sl * 16);
#pragma unroll
        for (int u = 0; u < 8; u++) accf8(a, t[u]);
    }
    for (; j + 2 <= end; j += 2) {
        uint4 t = *(const uint4*)(G + (size_t)col[j + h] * 512 + sl * 16);
        accf8(a, t);
    }
    if (j < end) {
        uint4 t = {0u, 0u, 0u, 0u};
        if (h == 0) t = *(const uint4*)(G + (size_t)col[j] * 512 + sl * 16);
        accf8(a, t);
    }
#pragma unroll
    for (int k = 0; k < 16; k++) a[k] += __shfl_xor(a[k], 32, 64);
    // epilogue: config c = sl>>2, feats fb = (sl&3)*16 .. +15
    int c = sl >> 2, fb = (sl & 3) * 16;
    size_t rowg = (size_t)wid * 8 + c;
    const u16* xpr = Y + rowg * 64 + fb;
    short8 x0 = ld_frag(xpr), x1 = ld_frag(xpr + 8);
    float v[16], sq = 0.f;
#pragma unroll
    for (int k = 0; k < 16; k++) {
        float xv = b2f((u16)(k < 8 ? x0[k] : x1[k - 8]));
        float val = xv + bp[fb + k] + lrelu(a[k] + bd[fb + k]);
        v[k] = val;
        sq += val * val;
    }
    sq += __shfl_xor(sq, 1, 64);
    sq += __shfl_xor(sq, 2, 64);
    float sc = rsqrtf(fmaxf(sq, 1e-12f));
    if (h == 0) {
        uint4 o0, o1;
        o0.x = pack2(v[0] * sc, v[1] * sc);   o0.y = pack2(v[2] * sc, v[3] * sc);
        o0.z = pack2(v[4] * sc, v[5] * sc);   o0.w = pack2(v[6] * sc, v[7] * sc);
        o1.x = pack2(v[8] * sc, v[9] * sc);   o1.y = pack2(v[10] * sc, v[11] * sc);
        o1.z = pack2(v[12] * sc, v[13] * sc); o1.w = pack2(v[14] * sc, v[15] * sc);
        *(uint4*)(Y + rowg * 64 + fb) = o0;
        *(uint4*)(Y + rowg * 64 + fb + 8) = o1;
    }
}

// ---------------- FUSED SpMM + combine (layers 1/2), fp8 gather, Y IN-PLACE ----------------
// One wave per node pair. Gather reads the fp8 snapshot G only; the bf16
// reads (p-path) and writes of Y touch exactly the 16 rows owned by this
// wave, read-before-write in program order -> in-place is race-free.
__global__ __launch_bounds__(256) void fused_spmm_f8_k(u16* __restrict__ Y,
                                                       const u8* __restrict__ G,
                                                       const int* __restrict__ row_ptr,
                                                       const int* __restrict__ col,
                                                       const u16* __restrict__ WdT,
                                                       const u16* __restrict__ WpT,
                                                       const float* __restrict__ bd,
                                                       const float* __restrict__ bp) {
    __shared__ u16 lds_t[4 * 16 * 72];
    int lane = threadIdx.x & 63;
    u16* L = lds_t + (threadIdx.x >> 6) * (16 * 72);
    int m = lane & 15, q = lane >> 4;
    int h = lane >> 5, sl = lane & 31;
    short8 bdf[4][2], bpf[4][2];
#pragma unroll
    for (int t = 0; t < 4; t++)
#pragma unroll
        for (int s = 0; s < 2; s++) {
            int off = (t * 16 + m) * 64 + s * 32 + q * 8;
            bdf[t][s] = ld_frag(WdT + off);
            bpf[t][s] = ld_frag(WpT + off);
        }
    float bdv[4], bpv[4];
#pragma unroll
    for (int t = 0; t < 4; t++) { bdv[t] = bd[t * 16 + m]; bpv[t] = bp[t * 16 + m]; }

    int wid = (blockIdx.x * 256 + threadIdx.x) >> 6;
    if (wid >= NN / 2) return;
    int pb = wid;
    {
        // p-path rows loaded FIRST (before any Y writes; wave-local rows)
        const u16* xr = Y + ((size_t)(pb * 16 + m)) * 64 + q * 8;
        short8 ax0 = ld_frag(xr), ax1 = ld_frag(xr + 32);
#pragma unroll
        for (int p = 0; p < 2; p++) {
            int node = pb * 2 + p;
            int start = row_ptr[node], end = row_ptr[node + 1];
            float a[16];
#pragma unroll
            for (int k = 0; k < 16; k++) a[k] = 0.f;
            int j = start;
            for (; j + 16 <= end; j += 16) {
                uint4 t[8];
#pragma unroll
                for (int u = 0; u < 8; u++)
                    t[u] = *(const uint4*)(G + (size_t)col[j + 2 * u + h] * 512 + sl * 16);
#pragma unroll
                for (int u = 0; u < 8; u++) accf8(a, t[u]);
            }
            for (; j + 2 <= end; j += 2) {
                uint4 t = *(const uint4*)(G + (size_t)col[j + h] * 512 + sl * 16);
                accf8(a, t);
            }
            if (j < end) {
                uint4 t = {0u, 0u, 0u, 0u};
                if (h == 0) t = *(const uint4*)(G + (size_t)col[j] * 512 + sl * 16);
                accf8(a, t);
            }
#pragma unroll
            for (int k = 0; k < 16; k++) a[k] += __shfl_xor(a[k], 32, 64);
            if (lane < 32) {
                // LDS row = p*8 + config(sl>>2), u16 col = (sl&3)*16 .. +15
                u16* Lr = L + (size_t)(p * 8 + (sl >> 2)) * 72 + (sl & 3) * 16;
                uint4 o0, o1;
                o0.x = pack2(a[0], a[1]);   o0.y = pack2(a[2], a[3]);
                o0.z = pack2(a[4], a[5]);   o0.w = pack2(a[6], a[7]);
                o1.x = pack2(a[8], a[9]);   o1.y = pack2(a[10], a[11]);
                o1.z = pack2(a[12], a[13]); o1.w = pack2(a[14], a[15]);
                *(uint4*)Lr = o0;
                *(uint4*)(Lr + 8) = o1;
            }
        }
        short8 ay0 = ld_frag(L + m * 72 + q * 8);
        short8 ay1 = ld_frag(L + m * 72 + 32 + q * 8);
        f32x4 ad[4], ap[4];
#pragma unroll
        for (int t = 0; t < 4; t++) {
            ad[t] = (f32x4){0.f, 0.f, 0.f, 0.f};
            ap[t] = (f32x4){0.f, 0.f, 0.f, 0.f};
        }
#pragma unroll
        for (int t = 0; t < 4; t++) {
            ad[t] = __builtin_amdgcn_mfma_f32_16x16x32_bf16(ay0, bdf[t][0], ad[t], 0, 0, 0);
            ad[t] = __builtin_amdgcn_mfma_f32_16x16x32_bf16(ay1, bdf[t][1], ad[t], 0, 0, 0);
            ap[t] = __builtin_amdgcn_mfma_f32_16x16x32_bf16(ax0, bpf[t][0], ap[t], 0, 0, 0);
            ap[t] = __builtin_amdgcn_mfma_f32_16x16x32_bf16(ax1, bpf[t][1], ap[t], 0, 0, 0);
        }
        float v[4][4], sq[4];
#pragma unroll
        for (int r = 0; r < 4; r++) sq[r] = 0.f;
#pragma unroll
        for (int t = 0; t < 4; t++)
#pragma unroll
            for (int r = 0; r < 4; r++) {
                float val = ap[t][r] + bpv[t] + lrelu(ad[t][r] + bdv[t]);
                v[t][r] = val;
                sq[r] += val * val;
            }
#pragma unroll
        for (int r = 0; r < 4; r++) {
#pragma unroll
            for (int mm = 1; mm < 16; mm <<= 1) sq[r] += __shfl_xor(sq[r], mm, 64);
            float sc = rsqrtf(fmaxf(sq[r], 1e-12f));
            u16* orow = Y + ((size_t)(pb * 16 + q * 4 + r)) * 64 + m;
#pragma unroll
            for (int t = 0; t < 4; t++) orow[t * 16] = (u16)f2b(v[t][r] * sc);
        }
    }
}

// ---------------- pooling: hierarchical + atomics ----------------
__global__ __launch_bounds__(256) void pool2_k(const u16* __restrict__ X,
                                               const int* __restrict__ graph_ids,
                                               float* __restrict__ pooled) {
    int chunk = (NN + gridDim.x - 1) / gridDim.x;
    int n0 = blockIdx.x * chunk;
    int n1 = min(n0 + chunk, NN);
    if (n0 >= n1) return;
    int f = threadIdx.x & 63;
    int c0 = threadIdx.x >> 6;          // 0..3 -> configs c0, c0+4
    float a0 = 0.f, a1 = 0.f;
    int cur = graph_ids[n0];
    for (int n = n0; n < n1; n++) {
        int g = graph_ids[n];
        if (g != cur) {
            atomicAdd(&pooled[(size_t)(cur * 8 + c0) * 64 + f], a0);
            atomicAdd(&pooled[(size_t)(cur * 8 + c0 + 4) * 64 + f], a1);
            a0 = 0.f; a1 = 0.f; cur = g;
        }
        a0 += b2f(X[((size_t)n * 8 + c0) * 64 + f]);
        a1 += b2f(X[((size_t)n * 8 + c0 + 4) * 64 + f]);
    }
    atomicAdd(&pooled[(size_t)(cur * 8 + c0) * 64 + f], a0);
    atomicAdd(&pooled[(size_t)(cur * 8 + c0 + 4) * 64 + f], a1);
}

// ---------------- final MLP over 128 (b,c) rows ----------------
__global__ __launch_bounds__(256) void mlp_k(const float* __restrict__ pooled,
                                             const float* __restrict__ W0, const float* __restrict__ b0,
                                             const float* __restrict__ W1, const float* __restrict__ b1,
                                             const float* __restrict__ W2, const float* __restrict__ b2,
                                             float* __restrict__ out) {
    int lane = threadIdx.x & 63;
    int row = blockIdx.x * 4 + (threadIdx.x >> 6);
    if (row >= BB * CC) return;
    float b0l = b0[lane], b1l = b1[lane], w2l = W2[lane], b2s = b2[0];
    float p = pooled[(size_t)row * 64 + lane];
    float a = 0.f;
    for (int k = 0; k < 64; k++) a = fmaf(rdlane(p, k), W0[k * 64 + lane], a);
    float h0 = lrelu(a + b0l);
    float a1 = 0.f;
    for (int k = 0; k < 64; k++) a1 = fmaf(rdlane(h0, k), W1[k * 64 + lane], a1);
    float h1 = lrelu(a1 + b1l);
    float v = wave_sum64(h1 * w2l);
    if (lane == 0) out[row] = v + b2s;
}

extern "C" void kernel_launch(void* const* d_in, const int* in_sizes, int n_in,
                              void* d_out, int out_size, void* d_ws, size_t ws_size,
                              hipStream_t stream) {
    const float* node_feats   = (const float*)d_in[0];
    const float* config_feats = (const float*)d_in[1];
    const int*   op_ids       = (const int*)d_in[2];
    const int*   src          = (const int*)d_in[3];
    const int*   dst          = (const int*)d_in[4];
    const int*   graph_ids    = (const int*)d_in[5];
    const float* op_emb       = (const float*)d_in[6];
    const float* W_d0 = (const float*)d_in[7],  *b_d0 = (const float*)d_in[8];
    const float* W_p0 = (const float*)d_in[9],  *b_p0 = (const float*)d_in[10];
    const float* W_d1 = (const float*)d_in[11], *b_d1 = (const float*)d_in[12];
    const float* W_p1 = (const float*)d_in[13], *b_p1 = (const float*)d_in[14];
    const float* W_d2 = (const float*)d_in[15], *b_d2 = (const float*)d_in[16];
    const float* W_p2 = (const float*)d_in[17], *b_p2 = (const float*)d_in[18];
    const float* W_m0 = (const float*)d_in[19], *b_m0 = (const float*)d_in[20];
    const float* W_m1 = (const float*)d_in[21], *b_m1 = (const float*)d_in[22];
    const float* W_m2 = (const float*)d_in[23], *b_m2 = (const float*)d_in[24];
    float* out = (float*)d_out;

    // workspace layout (~193.5 MB total) -- fits comfortably in the budget
    // that R12 (245MB) already ran in.
    char* ws = (char*)d_ws;
    size_t off = 0;
    u16* Y       = (u16*)(ws + off); off += (size_t)NROWS * 64 * 2;   // 102.4 MB
    u8*  G       = (u8*)(ws + off);  off += (size_t)NROWS * 64;       // 51.2 MB
    int* col     = (int*)(ws + off);   off += (size_t)2 * EE * 4;     // 12.8 MB
    int* row_ptr = (int*)(ws + off);   off += 400128;                 // N+1 padded
    u16* WT      = (u16*)(ws + off);   off += (4 * 4096 + 2 * 10240) * 2;
    float* pooled = (float*)(ws + off); off += BB * CC * 64 * 4;
    u16* nf_d    = (u16*)(ws + off); off += (size_t)NN * 64 * 2;      // 12.8 MB
    u16* nf_p    = (u16*)(ws + off); off += (size_t)NN * 64 * 2;      // 12.8 MB
    float* op_d  = (float*)(ws + off); off += 120 * 64 * 4;
    float* op_p  = (float*)(ws + off); off += 120 * 64 * 4;
    int* deg     = (int*)(ws + off);   off += 400128;
    int* cursor  = (int*)(ws + off);   off += 400128;
    int* bsum    = (int*)(ws + off);   off += 512;
    (void)ws_size; (void)in_sizes; (void)n_in; (void)out_size;

    const int NB = (NN + 1023) / 1024;   // 98 scan blocks
    const int NCONV = (NROWS * 64 / 8 + 255) / 256;  // 25000 blocks

    // ---- CSR build + weight prep ----
    hipMemsetAsync(deg, 0, (size_t)NN * 4, stream);
    hipMemsetAsync(pooled, 0, (size_t)BB * CC * 64 * 4, stream);
    deg_count_k<<<(2 * EE) / 256, 256, 0, stream>>>(src, dst, deg);
    prep_w_k<<<144, 256, 0, stream>>>(W_d1, W_p1, W_d2, W_p2,
                                      W_d0 + 64 * 64, W_p0 + 64 * 64, WT);
    scan1_k<<<NB, 1024, 0, stream>>>(deg, row_ptr, bsum, NN);
    scan2_k<<<1, 1, 0, stream>>>(bsum, NB);
    scan3_k<<<NB, 1024, 0, stream>>>(row_ptr, cursor, bsum, NN, NB);
    // chunked placement: 8 passes, each confining col writes to ~1.6MB
    {
        const int NCHUNK = 8;
        const int CSZ = (NN + NCHUNK - 1) / NCHUNK;   // 12500
        for (int c = 0; c < NCHUNK; c++) {
            int c0 = c * CSZ;
            int c1 = min(c0 + CSZ, NN);
            place_k<<<(2 * EE) / 256, 256, 0, stream>>>(src, dst, cursor, col, c0, c1);
        }
    }

    // ---- input projections: G = fp8 d-projection, Y = bf16 p-projection ----
    op_dp_k<<<30, 256, 0, stream>>>(op_emb, W_d0, W_p0, op_d, op_p);
    nf_mfma_k<<<512, 256, 0, stream>>>(node_feats, WT + 16384, WT + 16384 + 10240, nf_d, nf_p);
    hd0_dual_k<<<2048, 256, 0, stream>>>(G, Y, config_feats, op_ids, nf_d, nf_p,
                                         op_d, op_p, W_d0 + 204 * 64, W_p0 + 204 * 64);

    // ---- layer 0: gather G, combine in-place on Y ----
    fused_l0_f8_k<<<NN / 4, 256, 0, stream>>>(G, Y, row_ptr, col, b_d0, b_p0);
    // ---- layer 1: snapshot Y->G, fused SpMM+combine in-place on Y ----
    conv_fp8_k<<<NCONV, 256, 0, stream>>>(Y, (uint2*)G);
    fused_spmm_f8_k<<<12500, 256, 0, stream>>>(Y, G, row_ptr, col,
                                               WT, WT + 4096, b_d1, b_p1);
    // ---- layer 2: snapshot Y->G, fused SpMM+combine in-place on Y ----
    conv_fp8_k<<<NCONV, 256, 0, stream>>>(Y, (uint2*)G);
    fused_spmm_f8_k<<<12500, 256, 0, stream>>>(Y, G, row_ptr, col,
                                               WT + 8192, WT + 12288, b_d2, b_p2);

    // ---- pooling + MLP ----
    pool2_k<<<2048, 256, 0, stream>>>(Y, graph_ids, pooled);
    mlp_k<<<32, 256, 0, stream>>>(pooled, W_m0, b_m0, W_m1, b_m1, W_m2, b_m2, out);
}

// Round 8
// 2108.050 us; speedup vs baseline: 1.0786x; 1.0786x over previous
//
#include <hip/hip_runtime.h>
#include <hip/hip_bf16.h>

// Problem constants (match reference)
#define NN 100000
#define EE 1600000
#define CC 8
#define HH 64
#define NF 140
#define CF 18
#define BB 16
#define NROWS (NN * CC)          // 800000 rows of [64]
#define ALPHA 0.2f

// R16: fp8 gather with R12-shaped addressing (full-wave contiguous).
// R15 post-mortem: fp8 halved FETCH as predicted but the 2-edges-per-
// instruction split-wave addressing (two unrelated 512B segments per vector
// load) collapsed demand throughput 7.5 -> 3.0 TB/s. Measured ladder:
// 1KB-contig=7.5, 512B-contig(R9)=5.7, 2x512B-split(R15)=3.0 TB/s demand.
// Fix: one edge per instruction, full wave on ONE contiguous 512B segment
// (uint2/lane), unroll 16 -- identical lane mapping to R12, epilogues
// unchanged. fp8 precision already validated by R15 (passed, same absmax).
// KEPT: single bf16 buffer Y with in-place layers (R15), fp8 snapshot G,
// hd0 direct-fp8 emit, chunked place_k (R11/R12). Footprint ~193MB.
// Flow: hd0 -> G(fp8),Y(bf16) ; l0: gather G, Y in-place ; conv Y->G ;
// spmm1: gather G, Y in-place ; conv Y->G ; spmm2: in-place ; pool(Y).

typedef unsigned short u16;
typedef unsigned int u32;
typedef unsigned char u8;
typedef __attribute__((ext_vector_type(8))) short short8;   // 8 bf16 (4 VGPRs)
typedef __attribute__((ext_vector_type(4))) float f32x4;    // MFMA accum
typedef __attribute__((ext_vector_type(4))) float fv4;
typedef __attribute__((ext_vector_type(2))) float f32x2;

__device__ __forceinline__ float rdlane(float v, int l) {
    return __int_as_float(__builtin_amdgcn_readlane(__float_as_int(v), l));
}
__device__ __forceinline__ float lrelu(float x) { return x > 0.f ? x : ALPHA * x; }
__device__ __forceinline__ float wave_sum64(float v) {
#pragma unroll
    for (int m = 1; m < 64; m <<= 1) v += __shfl_xor(v, m, 64);
    return v;
}
__device__ __forceinline__ float b2f(u16 u) { return __uint_as_float(((u32)u) << 16); }
__device__ __forceinline__ u32 f2b(float f) {
    u32 u = __float_as_uint(f);
    return (u + 0x7fffu + ((u >> 16) & 1u)) >> 16;
}
__device__ __forceinline__ u32 pack2(float lo, float hi) {
    return f2b(lo) | (f2b(hi) << 16);
}
__device__ __forceinline__ short8 ld_frag(const u16* p) {
    union { uint4 u; short8 s; } c;
    c.u = *(const uint4*)p;
    return c.s;
}

// ---------------- fp8 e4m3 helpers ----------------
#if __has_builtin(__builtin_amdgcn_cvt_pk_f32_fp8) && __has_builtin(__builtin_amdgcn_cvt_pk_fp8_f32)
#define HAS_HW_FP8 1
#else
#define HAS_HW_FP8 0
#endif

__device__ __forceinline__ float dec8_sw(u32 b) {
    u32 u = ((b & 0x80u) << 24) | ((b & 0x7fu) << 20);
    return __uint_as_float(u) * 0x1.0p+120f;
}
__device__ __forceinline__ u32 enc8_sw(float f) {
    f = fminf(fmaxf(f, -448.f), 448.f);
    u32 u = __float_as_uint(f * 0x1.0p-120f);
    u32 r = u + 0x7ffffu + ((u >> 20) & 1u);
    return ((r >> 24) & 0x80u) | ((r >> 20) & 0x7fu);
}
__device__ __forceinline__ u32 pk4_fp8(float a, float b, float c, float d) {
#if HAS_HW_FP8
    u32 w = 0;
    w = __builtin_amdgcn_cvt_pk_fp8_f32(a, b, w, false);
    w = __builtin_amdgcn_cvt_pk_fp8_f32(c, d, w, true);
    return w;
#else
    return enc8_sw(a) | (enc8_sw(b) << 8) | (enc8_sw(c) << 16) | (enc8_sw(d) << 24);
#endif
}
// accumulate 8 fp8 values (one uint2) into a[8]
__device__ __forceinline__ void accf8(float* a, uint2 t) {
#if HAS_HW_FP8
    f32x2 d;
    d = __builtin_amdgcn_cvt_pk_f32_fp8(t.x, false); a[0] += d.x; a[1] += d.y;
    d = __builtin_amdgcn_cvt_pk_f32_fp8(t.x, true);  a[2] += d.x; a[3] += d.y;
    d = __builtin_amdgcn_cvt_pk_f32_fp8(t.y, false); a[4] += d.x; a[5] += d.y;
    d = __builtin_amdgcn_cvt_pk_f32_fp8(t.y, true);  a[6] += d.x; a[7] += d.y;
#else
    u32 w[2] = {t.x, t.y};
#pragma unroll
    for (int q = 0; q < 2; q++) {
        a[q*4+0] += dec8_sw(w[q] & 0xffu);
        a[q*4+1] += dec8_sw((w[q] >> 8) & 0xffu);
        a[q*4+2] += dec8_sw((w[q] >> 16) & 0xffu);
        a[q*4+3] += dec8_sw((w[q] >> 24) & 0xffu);
    }
#endif
}

// ---------------- CSR build ----------------
__global__ __launch_bounds__(256) void deg_count_k(const int* __restrict__ src,
                                                   const int* __restrict__ dst,
                                                   int* __restrict__ deg) {
    int e = blockIdx.x * 256 + threadIdx.x;
    if (e < EE) atomicAdd(&deg[dst[e]], 1);
    else if (e < 2 * EE) atomicAdd(&deg[src[e - EE]], 1);
}

__global__ __launch_bounds__(1024) void scan1_k(const int* __restrict__ deg,
                                                int* __restrict__ row_ptr,
                                                int* __restrict__ bsum, int n) {
    __shared__ int lds[17];
    int i = blockIdx.x * 1024 + threadIdx.x;
    int lane = threadIdx.x & 63, wv = threadIdx.x >> 6;
    int val = (i < n) ? deg[i] : 0;
    int v = val;
#pragma unroll
    for (int d = 1; d < 64; d <<= 1) {
        int t = __shfl_up(v, d, 64);
        if (lane >= d) v += t;
    }
    if (lane == 63) lds[wv] = v;
    __syncthreads();
    if (threadIdx.x == 0) {
        int run = 0;
#pragma unroll
        for (int k = 0; k < 16; k++) { int t = lds[k]; lds[k] = run; run += t; }
        lds[16] = run;
    }
    __syncthreads();
    if (i < n) row_ptr[i] = v - val + lds[wv];
    if (threadIdx.x == 1023) bsum[blockIdx.x] = lds[16];
}

__global__ void scan2_k(int* __restrict__ bsum, int nb) {
    int run = 0;
    for (int b = 0; b < nb; b++) { int t = bsum[b]; bsum[b] = run; run += t; }
    bsum[nb] = run;
}

__global__ __launch_bounds__(1024) void scan3_k(int* __restrict__ row_ptr,
                                                int* __restrict__ cursor,
                                                const int* __restrict__ bsum,
                                                int n, int nb) {
    int i = blockIdx.x * 1024 + threadIdx.x;
    if (i < n) {
        int v = row_ptr[i] + bsum[blockIdx.x];
        row_ptr[i] = v;
        cursor[i] = v;
    }
    if (i == 0) row_ptr[n] = bsum[nb];
}

// Chunked placement (R11): only edges whose dst node is in [c0,c1).
__global__ __launch_bounds__(256) void place_k(const int* __restrict__ src,
                                               const int* __restrict__ dst,
                                               int* __restrict__ cursor,
                                               int* __restrict__ col,
                                               int c0, int c1) {
    int e = blockIdx.x * 256 + threadIdx.x;
    int node, other;
    if (e < EE) { node = dst[e]; other = src[e]; }
    else if (e < 2 * EE) { node = src[e - EE]; other = dst[e - EE]; }
    else return;
    if (node < c0 || node >= c1) return;
    int pos = atomicAdd(&cursor[node], 1);
    col[pos] = other;
}

// ---------------- weight prep: transposed bf16 weights ----------------
__global__ __launch_bounds__(256) void prep_w_k(const float* __restrict__ Wd1, const float* __restrict__ Wp1,
                                                const float* __restrict__ Wd2, const float* __restrict__ Wp2,
                                                const float* __restrict__ Wd0nf, const float* __restrict__ Wp0nf,
                                                u16* __restrict__ WT) {
    int i = blockIdx.x * 256 + threadIdx.x;
    if (i < 4 * 4096) {
        int w = i >> 12, idx = i & 4095;
        int n = idx >> 6, k = idx & 63;
        const float* W = (w == 0) ? Wd1 : (w == 1) ? Wp1 : (w == 2) ? Wd2 : Wp2;
        WT[w * 4096 + n * 64 + k] = (u16)f2b(W[k * 64 + n]);
    } else {
        int j = i - 4 * 4096;
        if (j < 2 * 64 * 160) {
            int w = j / 10240, idx = j % 10240;
            int n = idx / 160, k = idx % 160;
            const float* W = w ? Wp0nf : Wd0nf;
            WT[16384 + w * 10240 + n * 160 + k] = (k < 140) ? (u16)f2b(W[k * 64 + n]) : (u16)0;
        }
    }
}

// op_d/op_p tables: [120][64] f32 = op_emb @ W_top (rows 0..63 of W_d0 / W_p0)
__global__ __launch_bounds__(256) void op_dp_k(const float* __restrict__ op_emb,
                                               const float* __restrict__ Wd_top,
                                               const float* __restrict__ Wp_top,
                                               float* __restrict__ op_d,
                                               float* __restrict__ op_p) {
    int lane = threadIdx.x & 63;
    int wid = (blockIdx.x * 256 + threadIdx.x) >> 6;
    if (wid >= 120) return;
    float v = op_emb[wid * 64 + lane];
    float ad = 0.f, ap = 0.f;
    for (int k = 0; k < 64; k++) {
        float s = rdlane(v, k);
        ad = fmaf(s, Wd_top[k * 64 + lane], ad);
        ap = fmaf(s, Wp_top[k * 64 + lane], ap);
    }
    op_d[wid * 64 + lane] = ad;
    op_p[wid * 64 + lane] = ap;
}

// ---------------- nf projections via MFMA ----------------
__global__ __launch_bounds__(256) void nf_mfma_k(const float* __restrict__ nf,
                                                 const u16* __restrict__ WdT0,
                                                 const u16* __restrict__ WpT0,
                                                 u16* __restrict__ nf_d,
                                                 u16* __restrict__ nf_p) {
    int lane = threadIdx.x & 63;
    int m = lane & 15, q = lane >> 4;
    int wid = (blockIdx.x * 256 + threadIdx.x) >> 6;
    int nw = (gridDim.x * 256) >> 6;
    for (int rb = wid; rb < NN / 16; rb += nw) {
        int node0 = rb * 16;
        const float* row = nf + (size_t)(node0 + m) * 140;
        short8 af[5];
#pragma unroll
        for (int s = 0; s < 5; s++) {
            int k0 = s * 32 + q * 8;
            float f[8];
            if (s < 4) {
                fv4 lo = __builtin_nontemporal_load((const fv4*)(row + k0));
                fv4 hi = __builtin_nontemporal_load((const fv4*)(row + k0 + 4));
                f[0]=lo.x; f[1]=lo.y; f[2]=lo.z; f[3]=lo.w;
                f[4]=hi.x; f[5]=hi.y; f[6]=hi.z; f[7]=hi.w;
            } else {
#pragma unroll
                for (int j = 0; j < 8; j++) f[j] = 0.f;
                if (q == 0) {
                    fv4 lo = __builtin_nontemporal_load((const fv4*)(row + 128));
                    fv4 hi = __builtin_nontemporal_load((const fv4*)(row + 132));
                    f[0]=lo.x; f[1]=lo.y; f[2]=lo.z; f[3]=lo.w;
                    f[4]=hi.x; f[5]=hi.y; f[6]=hi.z; f[7]=hi.w;
                } else if (q == 1) {
                    fv4 lo = __builtin_nontemporal_load((const fv4*)(row + 136));
                    f[0]=lo.x; f[1]=lo.y; f[2]=lo.z; f[3]=lo.w;
                }
            }
            short8 t;
#pragma unroll
            for (int j = 0; j < 8; j++) t[j] = (short)f2b(f[j]);
            af[s] = t;
        }
        f32x4 ad[4], ap[4];
#pragma unroll
        for (int t = 0; t < 4; t++) {
            ad[t] = (f32x4){0.f, 0.f, 0.f, 0.f};
            ap[t] = (f32x4){0.f, 0.f, 0.f, 0.f};
        }
#pragma unroll
        for (int s = 0; s < 5; s++) {
#pragma unroll
            for (int t = 0; t < 4; t++) {
                int boff = (t * 16 + m) * 160 + s * 32 + q * 8;
                short8 bdw = ld_frag(WdT0 + boff);
                short8 bpw = ld_frag(WpT0 + boff);
                ad[t] = __builtin_amdgcn_mfma_f32_16x16x32_bf16(af[s], bdw, ad[t], 0, 0, 0);
                ap[t] = __builtin_amdgcn_mfma_f32_16x16x32_bf16(af[s], bpw, ap[t], 0, 0, 0);
            }
        }
#pragma unroll
        for (int r = 0; r < 4; r++) {
            size_t nrow = (size_t)(node0 + q * 4 + r);
#pragma unroll
            for (int t = 0; t < 4; t++) {
                nf_d[nrow * 64 + t * 16 + m] = (u16)f2b(ad[t][r]);
                nf_p[nrow * 64 + t * 16 + m] = (u16)f2b(ap[t][r]);
            }
        }
    }
}

// hd0 v3: G[row] = fp8(op_d + nf_d + cf@WdBot) ; Y[row] = bf16(op_p + nf_p + cf@WpBot)
__global__ __launch_bounds__(256) void hd0_dual_k(u8* __restrict__ G,
                                                  u16* __restrict__ Y,
                                                  const float* __restrict__ cf,
                                                  const int* __restrict__ op_ids,
                                                  const u16* __restrict__ nf_d,
                                                  const u16* __restrict__ nf_p,
                                                  const float* __restrict__ op_d,
                                                  const float* __restrict__ op_p,
                                                  const float* __restrict__ WdBot,
                                                  const float* __restrict__ WpBot) {
    int lane = threadIdx.x & 63;
    float wbd[18], wbp[18];
#pragma unroll
    for (int k = 0; k < 18; k++) { wbd[k] = WdBot[k * 64 + lane]; wbp[k] = WpBot[k * 64 + lane]; }
    int wid = (blockIdx.x * 256 + threadIdx.x) >> 6;
    int nw = (gridDim.x * 256) >> 6;
    for (int row = wid; row < NROWS; row += nw) {
        int n = row >> 3;
        float cfv = (lane < 18) ? __builtin_nontemporal_load(cf + (size_t)row * 18 + lane) : 0.f;
        int op = op_ids[n];
        float accd = op_d[op * 64 + lane] + b2f(nf_d[(size_t)n * 64 + lane]);
        float accp = op_p[op * 64 + lane] + b2f(nf_p[(size_t)n * 64 + lane]);
#pragma unroll
        for (int k = 0; k < 18; k++) {
            float s = rdlane(cfv, k);
            accd = fmaf(s, wbd[k], accd);
            accp = fmaf(s, wbp[k], accp);
        }
        // pack 4 lanes' accd into one fp8 u32 (lane&3==0 writes)
        float f1 = __shfl_down(accd, 1, 64);
        float f2 = __shfl_down(accd, 2, 64);
        float f3 = __shfl_down(accd, 3, 64);
        if ((lane & 3) == 0)
            ((u32*)G)[(size_t)row * 16 + (lane >> 2)] = pk4_fp8(accd, f1, f2, f3);
        Y[(size_t)row * 64 + lane] = (u16)f2b(accp);
    }
}

// ---------------- bf16 -> fp8 mirror conversion ----------------
__global__ __launch_bounds__(256) void conv_fp8_k(const u16* __restrict__ src,
                                                  uint2* __restrict__ dst) {
    int i = blockIdx.x * 256 + threadIdx.x;   // each thread: 8 elems
    if (i >= NROWS * 64 / 8) return;
    short8 v = ld_frag(src + (size_t)i * 8);
    float f[8];
#pragma unroll
    for (int k = 0; k < 8; k++) f[k] = b2f((u16)v[k]);
    uint2 o;
    o.x = pk4_fp8(f[0], f[1], f[2], f[3]);
    o.y = pk4_fp8(f[4], f[5], f[6], f[7]);
    dst[i] = o;
}

// ---------------- FUSED layer 0: fp8 gather (full-wave contiguous), Y in-place ----------------
// One wave per node, one edge per load instruction: lane covers uint2
// (8 fp8) at byte lane*8 of the 512B node row -> config r=lane>>3, feats
// fb=(lane&7)*8..+7 (identical lane map to R12). Unroll 16.
__global__ __launch_bounds__(256) void fused_l0_f8_k(const u8* __restrict__ G,
                                                     u16* __restrict__ Y,
                                                     const int* __restrict__ row_ptr,
                                                     const int* __restrict__ col,
                                                     const float* __restrict__ bd,
                                                     const float* __restrict__ bp) {
    int wid = (blockIdx.x * 256 + threadIdx.x) >> 6;
    int lane = threadIdx.x & 63;
    if (wid >= NN) return;
    int r = lane >> 3, fb = (lane & 7) * 8;
    const uint2* G2 = (const uint2*)G;
    float bdv[8], bpv[8];
#pragma unroll
    for (int j = 0; j < 8; j++) { bdv[j] = bd[fb + j]; bpv[j] = bp[fb + j]; }
    int start = row_ptr[wid];
    int end = row_ptr[wid + 1];
    float a[8] = {0.f, 0.f, 0.f, 0.f, 0.f, 0.f, 0.f, 0.f};
    int j = start;
    for (; j + 16 <= end; j += 16) {
        uint2 t[16];
#pragma unroll
        for (int u = 0; u < 16; u++) t[u] = G2[(size_t)col[j + u] * 64 + lane];
#pragma unroll
        for (int u = 0; u < 16; u++) accf8(a, t[u]);
    }
    for (; j + 4 <= end; j += 4) {
        uint2 t[4];
#pragma unroll
        for (int u = 0; u < 4; u++) t[u] = G2[(size_t)col[j + u] * 64 + lane];
#pragma unroll
        for (int u = 0; u < 4; u++) accf8(a, t[u]);
    }
    for (; j < end; j++) {
        uint2 t0 = G2[(size_t)col[j] * 64 + lane];
        accf8(a, t0);
    }
    // epilogue (identical to R12, on Y)
    size_t rowg = (size_t)wid * 8 + r;
    short8 xp = ld_frag(Y + rowg * 64 + fb);
    float v[8], sq = 0.f;
#pragma unroll
    for (int q = 0; q < 8; q++) {
        float val = b2f((u16)xp[q]) + bpv[q] + lrelu(a[q] + bdv[q]);
        v[q] = val;
        sq += val * val;
    }
    sq += __shfl_xor(sq, 1, 64);
    sq += __shfl_xor(sq, 2, 64);
    sq += __shfl_xor(sq, 4, 64);
    float sc = rsqrtf(fmaxf(sq, 1e-12f));
    uint4 o;
    o.x = pack2(v[0] * sc, v[1] * sc);
    o.y = pack2(v[2] * sc, v[3] * sc);
    o.z = pack2(v[4] * sc, v[5] * sc);
    o.w = pack2(v[6] * sc, v[7] * sc);
    *(uint4*)(Y + rowg * 64 + fb) = o;
}

// ---------------- FUSED SpMM + combine (layers 1/2), fp8 gather, Y IN-PLACE ----------------
// One wave per node pair. Gather: full-wave contiguous 512B per edge from
// the fp8 snapshot G. p-path bf16 reads + writes of Y touch exactly this
// wave's 16 rows, read-before-write in program order -> in-place race-free.
__global__ __launch_bounds__(256) void fused_spmm_f8_k(u16* __restrict__ Y,
                                                       const u8* __restrict__ G,
                                                       const int* __restrict__ row_ptr,
                                                       const int* __restrict__ col,
                                                       const u16* __restrict__ WdT,
                                                       const u16* __restrict__ WpT,
                                                       const float* __restrict__ bd,
                                                       const float* __restrict__ bp) {
    __shared__ u16 lds_t[4 * 16 * 72];
    int lane = threadIdx.x & 63;
    u16* L = lds_t + (threadIdx.x >> 6) * (16 * 72);
    int m = lane & 15, q = lane >> 4;
    const uint2* G2 = (const uint2*)G;
    short8 bdf[4][2], bpf[4][2];
#pragma unroll
    for (int t = 0; t < 4; t++)
#pragma unroll
        for (int s = 0; s < 2; s++) {
            int off = (t * 16 + m) * 64 + s * 32 + q * 8;
            bdf[t][s] = ld_frag(WdT + off);
            bpf[t][s] = ld_frag(WpT + off);
        }
    float bdv[4], bpv[4];
#pragma unroll
    for (int t = 0; t < 4; t++) { bdv[t] = bd[t * 16 + m]; bpv[t] = bp[t * 16 + m]; }

    int wid = (blockIdx.x * 256 + threadIdx.x) >> 6;
    if (wid >= NN / 2) return;
    int pb = wid;
    {
        // p-path rows loaded FIRST (before any Y writes; wave-local rows)
        const u16* xr = Y + ((size_t)(pb * 16 + m)) * 64 + q * 8;
        short8 ax0 = ld_frag(xr), ax1 = ld_frag(xr + 32);
#pragma unroll
        for (int p = 0; p < 2; p++) {
            int node = pb * 2 + p;
            int start = row_ptr[node], end = row_ptr[node + 1];
            float a[8] = {0.f, 0.f, 0.f, 0.f, 0.f, 0.f, 0.f, 0.f};
            int j = start;
            for (; j + 16 <= end; j += 16) {
                uint2 t[16];
#pragma unroll
                for (int u = 0; u < 16; u++) t[u] = G2[(size_t)col[j + u] * 64 + lane];
#pragma unroll
                for (int u = 0; u < 16; u++) accf8(a, t[u]);
            }
            for (; j + 4 <= end; j += 4) {
                uint2 t[4];
#pragma unroll
                for (int u = 0; u < 4; u++) t[u] = G2[(size_t)col[j + u] * 64 + lane];
#pragma unroll
                for (int u = 0; u < 4; u++) accf8(a, t[u]);
            }
            for (; j < end; j++) {
                uint2 t0 = G2[(size_t)col[j] * 64 + lane];
                accf8(a, t0);
            }
            uint4 o;
            o.x = pack2(a[0], a[1]);
            o.y = pack2(a[2], a[3]);
            o.z = pack2(a[4], a[5]);
            o.w = pack2(a[6], a[7]);
            *(uint4*)(L + (size_t)(p * 8 + (lane >> 3)) * 72 + (lane & 7) * 8) = o;
        }
        short8 ay0 = ld_frag(L + m * 72 + q * 8);
        short8 ay1 = ld_frag(L + m * 72 + 32 + q * 8);
        f32x4 ad[4], ap[4];
#pragma unroll
        for (int t = 0; t < 4; t++) {
            ad[t] = (f32x4){0.f, 0.f, 0.f, 0.f};
            ap[t] = (f32x4){0.f, 0.f, 0.f, 0.f};
        }
#pragma unroll
        for (int t = 0; t < 4; t++) {
            ad[t] = __builtin_amdgcn_mfma_f32_16x16x32_bf16(ay0, bdf[t][0], ad[t], 0, 0, 0);
            ad[t] = __builtin_amdgcn_mfma_f32_16x16x32_bf16(ay1, bdf[t][1], ad[t], 0, 0, 0);
            ap[t] = __builtin_amdgcn_mfma_f32_16x16x32_bf16(ax0, bpf[t][0], ap[t], 0, 0, 0);
            ap[t] = __builtin_amdgcn_mfma_f32_16x16x32_bf16(ax1, bpf[t][1], ap[t], 0, 0, 0);
        }
        float v[4][4], sq[4];
#pragma unroll
        for (int r = 0; r < 4; r++) sq[r] = 0.f;
#pragma unroll
        for (int t = 0; t < 4; t++)
#pragma unroll
            for (int r = 0; r < 4; r++) {
                float val = ap[t][r] + bpv[t] + lrelu(ad[t][r] + bdv[t]);
                v[t][r] = val;
                sq[r] += val * val;
            }
#pragma unroll
        for (int r = 0; r < 4; r++) {
#pragma unroll
            for (int mm = 1; mm < 16; mm <<= 1) sq[r] += __shfl_xor(sq[r], mm, 64);
            float sc = rsqrtf(fmaxf(sq[r], 1e-12f));
            u16* orow = Y + ((size_t)(pb * 16 + q * 4 + r)) * 64 + m;
#pragma unroll
            for (int t = 0; t < 4; t++) orow[t * 16] = (u16)f2b(v[t][r] * sc);
        }
    }
}

// ---------------- pooling: hierarchical + atomics ----------------
__global__ __launch_bounds__(256) void pool2_k(const u16* __restrict__ X,
                                               const int* __restrict__ graph_ids,
                                               float* __restrict__ pooled) {
    int chunk = (NN + gridDim.x - 1) / gridDim.x;
    int n0 = blockIdx.x * chunk;
    int n1 = min(n0 + chunk, NN);
    if (n0 >= n1) return;
    int f = threadIdx.x & 63;
    int c0 = threadIdx.x >> 6;          // 0..3 -> configs c0, c0+4
    float a0 = 0.f, a1 = 0.f;
    int cur = graph_ids[n0];
    for (int n = n0; n < n1; n++) {
        int g = graph_ids[n];
        if (g != cur) {
            atomicAdd(&pooled[(size_t)(cur * 8 + c0) * 64 + f], a0);
            atomicAdd(&pooled[(size_t)(cur * 8 + c0 + 4) * 64 + f], a1);
            a0 = 0.f; a1 = 0.f; cur = g;
        }
        a0 += b2f(X[((size_t)n * 8 + c0) * 64 + f]);
        a1 += b2f(X[((size_t)n * 8 + c0 + 4) * 64 + f]);
    }
    atomicAdd(&pooled[(size_t)(cur * 8 + c0) * 64 + f], a0);
    atomicAdd(&pooled[(size_t)(cur * 8 + c0 + 4) * 64 + f], a1);
}

// ---------------- final MLP over 128 (b,c) rows ----------------
__global__ __launch_bounds__(256) void mlp_k(const float* __restrict__ pooled,
                                             const float* __restrict__ W0, const float* __restrict__ b0,
                                             const float* __restrict__ W1, const float* __restrict__ b1,
                                             const float* __restrict__ W2, const float* __restrict__ b2,
                                             float* __restrict__ out) {
    int lane = threadIdx.x & 63;
    int row = blockIdx.x * 4 + (threadIdx.x >> 6);
    if (row >= BB * CC) return;
    float b0l = b0[lane], b1l = b1[lane], w2l = W2[lane], b2s = b2[0];
    float p = pooled[(size_t)row * 64 + lane];
    float a = 0.f;
    for (int k = 0; k < 64; k++) a = fmaf(rdlane(p, k), W0[k * 64 + lane], a);
    float h0 = lrelu(a + b0l);
    float a1 = 0.f;
    for (int k = 0; k < 64; k++) a1 = fmaf(rdlane(h0, k), W1[k * 64 + lane], a1);
    float h1 = lrelu(a1 + b1l);
    float v = wave_sum64(h1 * w2l);
    if (lane == 0) out[row] = v + b2s;
}

extern "C" void kernel_launch(void* const* d_in, const int* in_sizes, int n_in,
                              void* d_out, int out_size, void* d_ws, size_t ws_size,
                              hipStream_t stream) {
    const float* node_feats   = (const float*)d_in[0];
    const float* config_feats = (const float*)d_in[1];
    const int*   op_ids       = (const int*)d_in[2];
    const int*   src          = (const int*)d_in[3];
    const int*   dst          = (const int*)d_in[4];
    const int*   graph_ids    = (const int*)d_in[5];
    const float* op_emb       = (const float*)d_in[6];
    const float* W_d0 = (const float*)d_in[7],  *b_d0 = (const float*)d_in[8];
    const float* W_p0 = (const float*)d_in[9],  *b_p0 = (const float*)d_in[10];
    const float* W_d1 = (const float*)d_in[11], *b_d1 = (const float*)d_in[12];
    const float* W_p1 = (const float*)d_in[13], *b_p1 = (const float*)d_in[14];
    const float* W_d2 = (const float*)d_in[15], *b_d2 = (const float*)d_in[16];
    const float* W_p2 = (const float*)d_in[17], *b_p2 = (const float*)d_in[18];
    const float* W_m0 = (const float*)d_in[19], *b_m0 = (const float*)d_in[20];
    const float* W_m1 = (const float*)d_in[21], *b_m1 = (const float*)d_in[22];
    const float* W_m2 = (const float*)d_in[23], *b_m2 = (const float*)d_in[24];
    float* out = (float*)d_out;

    // workspace layout (~193.5 MB total)
    char* ws = (char*)d_ws;
    size_t off = 0;
    u16* Y       = (u16*)(ws + off); off += (size_t)NROWS * 64 * 2;   // 102.4 MB
    u8*  G       = (u8*)(ws + off);  off += (size_t)NROWS * 64;       // 51.2 MB
    int* col     = (int*)(ws + off);   off += (size_t)2 * EE * 4;     // 12.8 MB
    int* row_ptr = (int*)(ws + off);   off += 400128;                 // N+1 padded
    u16* WT      = (u16*)(ws + off);   off += (4 * 4096 + 2 * 10240) * 2;
    float* pooled = (float*)(ws + off); off += BB * CC * 64 * 4;
    u16* nf_d    = (u16*)(ws + off); off += (size_t)NN * 64 * 2;      // 12.8 MB
    u16* nf_p    = (u16*)(ws + off); off += (size_t)NN * 64 * 2;      // 12.8 MB
    float* op_d  = (float*)(ws + off); off += 120 * 64 * 4;
    float* op_p  = (float*)(ws + off); off += 120 * 64 * 4;
    int* deg     = (int*)(ws + off);   off += 400128;
    int* cursor  = (int*)(ws + off);   off += 400128;
    int* bsum    = (int*)(ws + off);   off += 512;
    (void)ws_size; (void)in_sizes; (void)n_in; (void)out_size;

    const int NB = (NN + 1023) / 1024;   // 98 scan blocks
    const int NCONV = (NROWS * 64 / 8 + 255) / 256;  // 25000 blocks

    // ---- CSR build + weight prep ----
    hipMemsetAsync(deg, 0, (size_t)NN * 4, stream);
    hipMemsetAsync(pooled, 0, (size_t)BB * CC * 64 * 4, stream);
    deg_count_k<<<(2 * EE) / 256, 256, 0, stream>>>(src, dst, deg);
    prep_w_k<<<144, 256, 0, stream>>>(W_d1, W_p1, W_d2, W_p2,
                                      W_d0 + 64 * 64, W_p0 + 64 * 64, WT);
    scan1_k<<<NB, 1024, 0, stream>>>(deg, row_ptr, bsum, NN);
    scan2_k<<<1, 1, 0, stream>>>(bsum, NB);
    scan3_k<<<NB, 1024, 0, stream>>>(row_ptr, cursor, bsum, NN, NB);
    // chunked placement: 8 passes, each confining col writes to ~1.6MB
    {
        const int NCHUNK = 8;
        const int CSZ = (NN + NCHUNK - 1) / NCHUNK;   // 12500
        for (int c = 0; c < NCHUNK; c++) {
            int c0 = c * CSZ;
            int c1 = min(c0 + CSZ, NN);
            place_k<<<(2 * EE) / 256, 256, 0, stream>>>(src, dst, cursor, col, c0, c1);
        }
    }

    // ---- input projections: G = fp8 d-projection, Y = bf16 p-projection ----
    op_dp_k<<<30, 256, 0, stream>>>(op_emb, W_d0, W_p0, op_d, op_p);
    nf_mfma_k<<<512, 256, 0, stream>>>(node_feats, WT + 16384, WT + 16384 + 10240, nf_d, nf_p);
    hd0_dual_k<<<2048, 256, 0, stream>>>(G, Y, config_feats, op_ids, nf_d, nf_p,
                                         op_d, op_p, W_d0 + 204 * 64, W_p0 + 204 * 64);

    // ---- layer 0: gather G, combine in-place on Y ----
    fused_l0_f8_k<<<NN / 4, 256, 0, stream>>>(G, Y, row_ptr, col, b_d0, b_p0);
    // ---- layer 1: snapshot Y->G, fused SpMM+combine in-place on Y ----
    conv_fp8_k<<<NCONV, 256, 0, stream>>>(Y, (uint2*)G);
    fused_spmm_f8_k<<<12500, 256, 0, stream>>>(Y, G, row_ptr, col,
                                               WT, WT + 4096, b_d1, b_p1);
    // ---- layer 2: snapshot Y->G, fused SpMM+combine in-place on Y ----
    conv_fp8_k<<<NCONV, 256, 0, stream>>>(Y, (uint2*)G);
    fused_spmm_f8_k<<<12500, 256, 0, stream>>>(Y, G, row_ptr, col,
                                               WT + 8192, WT + 12288, b_d2, b_p2);

    // ---- pooling + MLP ----
    pool2_k<<<2048, 256, 0, stream>>>(Y, graph_ids, pooled);
    mlp_k<<<32, 256, 0, stream>>>(pooled, W_m0, b_m0, W_m1, b_m1, W_m2, b_m2, out);
}

// Round 9
// 1535.934 us; speedup vs baseline: 1.4804x; 1.3725x over previous
//
#include <hip/hip_runtime.h>
#include <hip/hip_bf16.h>

// Problem constants (match reference)
#define NN 100000
#define EE 1600000
#define CC 8
#define HH 64
#define NF 140
#define CF 18
#define BB 16
#define NROWS (NN * CC)          // 800000 rows of [64]
#define ALPHA 0.2f

// R17: fix spmm_f8 occupancy (register-streamed epilogue).
// R16 post-mortem: l0_f8 hit ~240us (fp8 + full-wave-contiguous gather
// works at VGPR 64 / 37% occ), but spmm_f8 stalled at 557us with VGPR 132 /
// 10.5% occ -- crossing the 128-VGPR boundary cost a wave/SIMD and the
// concurrency-bound gather followed (bytes-in-flight ~28KB/CU -> 2.9 TB/s).
// Fix: stream the epilogue over the 4 output tiles (#pragma unroll 1):
// per-t reload of weight fragments from WT (L1/L2-resident, 16KB), reused
// f32x4 accumulators. All epilogue loads moved AFTER the gather. Peak VGPR
// ~max(gather 60, epilogue 80).
// KEPT: fp8 snapshot G + single in-place bf16 Y (R15/R16), hd0 direct-fp8
// emit, chunked place_k. Footprint ~193MB.
// Flow: hd0 -> G(fp8),Y(bf16) ; l0: gather G, Y in-place ; conv Y->G ;
// spmm1: gather G, Y in-place ; conv Y->G ; spmm2: in-place ; pool(Y).

typedef unsigned short u16;
typedef unsigned int u32;
typedef unsigned char u8;
typedef __attribute__((ext_vector_type(8))) short short8;   // 8 bf16 (4 VGPRs)
typedef __attribute__((ext_vector_type(4))) float f32x4;    // MFMA accum
typedef __attribute__((ext_vector_type(4))) float fv4;
typedef __attribute__((ext_vector_type(2))) float f32x2;

__device__ __forceinline__ float rdlane(float v, int l) {
    return __int_as_float(__builtin_amdgcn_readlane(__float_as_int(v), l));
}
__device__ __forceinline__ float lrelu(float x) { return x > 0.f ? x : ALPHA * x; }
__device__ __forceinline__ float wave_sum64(float v) {
#pragma unroll
    for (int m = 1; m < 64; m <<= 1) v += __shfl_xor(v, m, 64);
    return v;
}
__device__ __forceinline__ float b2f(u16 u) { return __uint_as_float(((u32)u) << 16); }
__device__ __forceinline__ u32 f2b(float f) {
    u32 u = __float_as_uint(f);
    return (u + 0x7fffu + ((u >> 16) & 1u)) >> 16;
}
__device__ __forceinline__ u32 pack2(float lo, float hi) {
    return f2b(lo) | (f2b(hi) << 16);
}
__device__ __forceinline__ short8 ld_frag(const u16* p) {
    union { uint4 u; short8 s; } c;
    c.u = *(const uint4*)p;
    return c.s;
}

// ---------------- fp8 e4m3 helpers ----------------
#if __has_builtin(__builtin_amdgcn_cvt_pk_f32_fp8) && __has_builtin(__builtin_amdgcn_cvt_pk_fp8_f32)
#define HAS_HW_FP8 1
#else
#define HAS_HW_FP8 0
#endif

__device__ __forceinline__ float dec8_sw(u32 b) {
    u32 u = ((b & 0x80u) << 24) | ((b & 0x7fu) << 20);
    return __uint_as_float(u) * 0x1.0p+120f;
}
__device__ __forceinline__ u32 enc8_sw(float f) {
    f = fminf(fmaxf(f, -448.f), 448.f);
    u32 u = __float_as_uint(f * 0x1.0p-120f);
    u32 r = u + 0x7ffffu + ((u >> 20) & 1u);
    return ((r >> 24) & 0x80u) | ((r >> 20) & 0x7fu);
}
__device__ __forceinline__ u32 pk4_fp8(float a, float b, float c, float d) {
#if HAS_HW_FP8
    u32 w = 0;
    w = __builtin_amdgcn_cvt_pk_fp8_f32(a, b, w, false);
    w = __builtin_amdgcn_cvt_pk_fp8_f32(c, d, w, true);
    return w;
#else
    return enc8_sw(a) | (enc8_sw(b) << 8) | (enc8_sw(c) << 16) | (enc8_sw(d) << 24);
#endif
}
// accumulate 8 fp8 values (one uint2) into a[8]
__device__ __forceinline__ void accf8(float* a, uint2 t) {
#if HAS_HW_FP8
    f32x2 d;
    d = __builtin_amdgcn_cvt_pk_f32_fp8(t.x, false); a[0] += d.x; a[1] += d.y;
    d = __builtin_amdgcn_cvt_pk_f32_fp8(t.x, true);  a[2] += d.x; a[3] += d.y;
    d = __builtin_amdgcn_cvt_pk_f32_fp8(t.y, false); a[4] += d.x; a[5] += d.y;
    d = __builtin_amdgcn_cvt_pk_f32_fp8(t.y, true);  a[6] += d.x; a[7] += d.y;
#else
    u32 w[2] = {t.x, t.y};
#pragma unroll
    for (int q = 0; q < 2; q++) {
        a[q*4+0] += dec8_sw(w[q] & 0xffu);
        a[q*4+1] += dec8_sw((w[q] >> 8) & 0xffu);
        a[q*4+2] += dec8_sw((w[q] >> 16) & 0xffu);
        a[q*4+3] += dec8_sw((w[q] >> 24) & 0xffu);
    }
#endif
}

// ---------------- CSR build ----------------
__global__ __launch_bounds__(256) void deg_count_k(const int* __restrict__ src,
                                                   const int* __restrict__ dst,
                                                   int* __restrict__ deg) {
    int e = blockIdx.x * 256 + threadIdx.x;
    if (e < EE) atomicAdd(&deg[dst[e]], 1);
    else if (e < 2 * EE) atomicAdd(&deg[src[e - EE]], 1);
}

__global__ __launch_bounds__(1024) void scan1_k(const int* __restrict__ deg,
                                                int* __restrict__ row_ptr,
                                                int* __restrict__ bsum, int n) {
    __shared__ int lds[17];
    int i = blockIdx.x * 1024 + threadIdx.x;
    int lane = threadIdx.x & 63, wv = threadIdx.x >> 6;
    int val = (i < n) ? deg[i] : 0;
    int v = val;
#pragma unroll
    for (int d = 1; d < 64; d <<= 1) {
        int t = __shfl_up(v, d, 64);
        if (lane >= d) v += t;
    }
    if (lane == 63) lds[wv] = v;
    __syncthreads();
    if (threadIdx.x == 0) {
        int run = 0;
#pragma unroll
        for (int k = 0; k < 16; k++) { int t = lds[k]; lds[k] = run; run += t; }
        lds[16] = run;
    }
    __syncthreads();
    if (i < n) row_ptr[i] = v - val + lds[wv];
    if (threadIdx.x == 1023) bsum[blockIdx.x] = lds[16];
}

__global__ void scan2_k(int* __restrict__ bsum, int nb) {
    int run = 0;
    for (int b = 0; b < nb; b++) { int t = bsum[b]; bsum[b] = run; run += t; }
    bsum[nb] = run;
}

__global__ __launch_bounds__(1024) void scan3_k(int* __restrict__ row_ptr,
                                                int* __restrict__ cursor,
                                                const int* __restrict__ bsum,
                                                int n, int nb) {
    int i = blockIdx.x * 1024 + threadIdx.x;
    if (i < n) {
        int v = row_ptr[i] + bsum[blockIdx.x];
        row_ptr[i] = v;
        cursor[i] = v;
    }
    if (i == 0) row_ptr[n] = bsum[nb];
}

// Chunked placement (R11): only edges whose dst node is in [c0,c1).
__global__ __launch_bounds__(256) void place_k(const int* __restrict__ src,
                                               const int* __restrict__ dst,
                                               int* __restrict__ cursor,
                                               int* __restrict__ col,
                                               int c0, int c1) {
    int e = blockIdx.x * 256 + threadIdx.x;
    int node, other;
    if (e < EE) { node = dst[e]; other = src[e]; }
    else if (e < 2 * EE) { node = src[e - EE]; other = dst[e - EE]; }
    else return;
    if (node < c0 || node >= c1) return;
    int pos = atomicAdd(&cursor[node], 1);
    col[pos] = other;
}

// ---------------- weight prep: transposed bf16 weights ----------------
__global__ __launch_bounds__(256) void prep_w_k(const float* __restrict__ Wd1, const float* __restrict__ Wp1,
                                                const float* __restrict__ Wd2, const float* __restrict__ Wp2,
                                                const float* __restrict__ Wd0nf, const float* __restrict__ Wp0nf,
                                                u16* __restrict__ WT) {
    int i = blockIdx.x * 256 + threadIdx.x;
    if (i < 4 * 4096) {
        int w = i >> 12, idx = i & 4095;
        int n = idx >> 6, k = idx & 63;
        const float* W = (w == 0) ? Wd1 : (w == 1) ? Wp1 : (w == 2) ? Wd2 : Wp2;
        WT[w * 4096 + n * 64 + k] = (u16)f2b(W[k * 64 + n]);
    } else {
        int j = i - 4 * 4096;
        if (j < 2 * 64 * 160) {
            int w = j / 10240, idx = j % 10240;
            int n = idx / 160, k = idx % 160;
            const float* W = w ? Wp0nf : Wd0nf;
            WT[16384 + w * 10240 + n * 160 + k] = (k < 140) ? (u16)f2b(W[k * 64 + n]) : (u16)0;
        }
    }
}

// op_d/op_p tables: [120][64] f32 = op_emb @ W_top (rows 0..63 of W_d0 / W_p0)
__global__ __launch_bounds__(256) void op_dp_k(const float* __restrict__ op_emb,
                                               const float* __restrict__ Wd_top,
                                               const float* __restrict__ Wp_top,
                                               float* __restrict__ op_d,
                                               float* __restrict__ op_p) {
    int lane = threadIdx.x & 63;
    int wid = (blockIdx.x * 256 + threadIdx.x) >> 6;
    if (wid >= 120) return;
    float v = op_emb[wid * 64 + lane];
    float ad = 0.f, ap = 0.f;
    for (int k = 0; k < 64; k++) {
        float s = rdlane(v, k);
        ad = fmaf(s, Wd_top[k * 64 + lane], ad);
        ap = fmaf(s, Wp_top[k * 64 + lane], ap);
    }
    op_d[wid * 64 + lane] = ad;
    op_p[wid * 64 + lane] = ap;
}

// ---------------- nf projections via MFMA ----------------
__global__ __launch_bounds__(256) void nf_mfma_k(const float* __restrict__ nf,
                                                 const u16* __restrict__ WdT0,
                                                 const u16* __restrict__ WpT0,
                                                 u16* __restrict__ nf_d,
                                                 u16* __restrict__ nf_p) {
    int lane = threadIdx.x & 63;
    int m = lane & 15, q = lane >> 4;
    int wid = (blockIdx.x * 256 + threadIdx.x) >> 6;
    int nw = (gridDim.x * 256) >> 6;
    for (int rb = wid; rb < NN / 16; rb += nw) {
        int node0 = rb * 16;
        const float* row = nf + (size_t)(node0 + m) * 140;
        short8 af[5];
#pragma unroll
        for (int s = 0; s < 5; s++) {
            int k0 = s * 32 + q * 8;
            float f[8];
            if (s < 4) {
                fv4 lo = __builtin_nontemporal_load((const fv4*)(row + k0));
                fv4 hi = __builtin_nontemporal_load((const fv4*)(row + k0 + 4));
                f[0]=lo.x; f[1]=lo.y; f[2]=lo.z; f[3]=lo.w;
                f[4]=hi.x; f[5]=hi.y; f[6]=hi.z; f[7]=hi.w;
            } else {
#pragma unroll
                for (int j = 0; j < 8; j++) f[j] = 0.f;
                if (q == 0) {
                    fv4 lo = __builtin_nontemporal_load((const fv4*)(row + 128));
                    fv4 hi = __builtin_nontemporal_load((const fv4*)(row + 132));
                    f[0]=lo.x; f[1]=lo.y; f[2]=lo.z; f[3]=lo.w;
                    f[4]=hi.x; f[5]=hi.y; f[6]=hi.z; f[7]=hi.w;
                } else if (q == 1) {
                    fv4 lo = __builtin_nontemporal_load((const fv4*)(row + 136));
                    f[0]=lo.x; f[1]=lo.y; f[2]=lo.z; f[3]=lo.w;
                }
            }
            short8 t;
#pragma unroll
            for (int j = 0; j < 8; j++) t[j] = (short)f2b(f[j]);
            af[s] = t;
        }
        f32x4 ad[4], ap[4];
#pragma unroll
        for (int t = 0; t < 4; t++) {
            ad[t] = (f32x4){0.f, 0.f, 0.f, 0.f};
            ap[t] = (f32x4){0.f, 0.f, 0.f, 0.f};
        }
#pragma unroll
        for (int s = 0; s < 5; s++) {
#pragma unroll
            for (int t = 0; t < 4; t++) {
                int boff = (t * 16 + m) * 160 + s * 32 + q * 8;
                short8 bdw = ld_frag(WdT0 + boff);
                short8 bpw = ld_frag(WpT0 + boff);
                ad[t] = __builtin_amdgcn_mfma_f32_16x16x32_bf16(af[s], bdw, ad[t], 0, 0, 0);
                ap[t] = __builtin_amdgcn_mfma_f32_16x16x32_bf16(af[s], bpw, ap[t], 0, 0, 0);
            }
        }
#pragma unroll
        for (int r = 0; r < 4; r++) {
            size_t nrow = (size_t)(node0 + q * 4 + r);
#pragma unroll
            for (int t = 0; t < 4; t++) {
                nf_d[nrow * 64 + t * 16 + m] = (u16)f2b(ad[t][r]);
                nf_p[nrow * 64 + t * 16 + m] = (u16)f2b(ap[t][r]);
            }
        }
    }
}

// hd0 v3: G[row] = fp8(op_d + nf_d + cf@WdBot) ; Y[row] = bf16(op_p + nf_p + cf@WpBot)
__global__ __launch_bounds__(256) void hd0_dual_k(u8* __restrict__ G,
                                                  u16* __restrict__ Y,
                                                  const float* __restrict__ cf,
                                                  const int* __restrict__ op_ids,
                                                  const u16* __restrict__ nf_d,
                                                  const u16* __restrict__ nf_p,
                                                  const float* __restrict__ op_d,
                                                  const float* __restrict__ op_p,
                                                  const float* __restrict__ WdBot,
                                                  const float* __restrict__ WpBot) {
    int lane = threadIdx.x & 63;
    float wbd[18], wbp[18];
#pragma unroll
    for (int k = 0; k < 18; k++) { wbd[k] = WdBot[k * 64 + lane]; wbp[k] = WpBot[k * 64 + lane]; }
    int wid = (blockIdx.x * 256 + threadIdx.x) >> 6;
    int nw = (gridDim.x * 256) >> 6;
    for (int row = wid; row < NROWS; row += nw) {
        int n = row >> 3;
        float cfv = (lane < 18) ? __builtin_nontemporal_load(cf + (size_t)row * 18 + lane) : 0.f;
        int op = op_ids[n];
        float accd = op_d[op * 64 + lane] + b2f(nf_d[(size_t)n * 64 + lane]);
        float accp = op_p[op * 64 + lane] + b2f(nf_p[(size_t)n * 64 + lane]);
#pragma unroll
        for (int k = 0; k < 18; k++) {
            float s = rdlane(cfv, k);
            accd = fmaf(s, wbd[k], accd);
            accp = fmaf(s, wbp[k], accp);
        }
        // pack 4 lanes' accd into one fp8 u32 (lane&3==0 writes)
        float f1 = __shfl_down(accd, 1, 64);
        float f2 = __shfl_down(accd, 2, 64);
        float f3 = __shfl_down(accd, 3, 64);
        if ((lane & 3) == 0)
            ((u32*)G)[(size_t)row * 16 + (lane >> 2)] = pk4_fp8(accd, f1, f2, f3);
        Y[(size_t)row * 64 + lane] = (u16)f2b(accp);
    }
}

// ---------------- bf16 -> fp8 mirror conversion ----------------
__global__ __launch_bounds__(256) void conv_fp8_k(const u16* __restrict__ src,
                                                  uint2* __restrict__ dst) {
    int i = blockIdx.x * 256 + threadIdx.x;   // each thread: 8 elems
    if (i >= NROWS * 64 / 8) return;
    short8 v = ld_frag(src + (size_t)i * 8);
    float f[8];
#pragma unroll
    for (int k = 0; k < 8; k++) f[k] = b2f((u16)v[k]);
    uint2 o;
    o.x = pk4_fp8(f[0], f[1], f[2], f[3]);
    o.y = pk4_fp8(f[4], f[5], f[6], f[7]);
    dst[i] = o;
}

// ---------------- FUSED layer 0: fp8 gather (full-wave contiguous), Y in-place ----------------
// One wave per node, one edge per load instruction: lane covers uint2
// (8 fp8) at byte lane*8 of the 512B node row -> config r=lane>>3, feats
// fb=(lane&7)*8..+7 (identical lane map to R12). Unroll 16.
__global__ __launch_bounds__(256) void fused_l0_f8_k(const u8* __restrict__ G,
                                                     u16* __restrict__ Y,
                                                     const int* __restrict__ row_ptr,
                                                     const int* __restrict__ col,
                                                     const float* __restrict__ bd,
                                                     const float* __restrict__ bp) {
    int wid = (blockIdx.x * 256 + threadIdx.x) >> 6;
    int lane = threadIdx.x & 63;
    if (wid >= NN) return;
    int r = lane >> 3, fb = (lane & 7) * 8;
    const uint2* G2 = (const uint2*)G;
    int start = row_ptr[wid];
    int end = row_ptr[wid + 1];
    float a[8] = {0.f, 0.f, 0.f, 0.f, 0.f, 0.f, 0.f, 0.f};
    int j = start;
    for (; j + 16 <= end; j += 16) {
        uint2 t[16];
#pragma unroll
        for (int u = 0; u < 16; u++) t[u] = G2[(size_t)col[j + u] * 64 + lane];
#pragma unroll
        for (int u = 0; u < 16; u++) accf8(a, t[u]);
    }
    for (; j + 4 <= end; j += 4) {
        uint2 t[4];
#pragma unroll
        for (int u = 0; u < 4; u++) t[u] = G2[(size_t)col[j + u] * 64 + lane];
#pragma unroll
        for (int u = 0; u < 4; u++) accf8(a, t[u]);
    }
    for (; j < end; j++) {
        uint2 t0 = G2[(size_t)col[j] * 64 + lane];
        accf8(a, t0);
    }
    // epilogue (loads after gather; identical math to R12, on Y)
    float bdv[8], bpv[8];
#pragma unroll
    for (int jj = 0; jj < 8; jj++) { bdv[jj] = bd[fb + jj]; bpv[jj] = bp[fb + jj]; }
    size_t rowg = (size_t)wid * 8 + r;
    short8 xp = ld_frag(Y + rowg * 64 + fb);
    float v[8], sq = 0.f;
#pragma unroll
    for (int q = 0; q < 8; q++) {
        float val = b2f((u16)xp[q]) + bpv[q] + lrelu(a[q] + bdv[q]);
        v[q] = val;
        sq += val * val;
    }
    sq += __shfl_xor(sq, 1, 64);
    sq += __shfl_xor(sq, 2, 64);
    sq += __shfl_xor(sq, 4, 64);
    float sc = rsqrtf(fmaxf(sq, 1e-12f));
    uint4 o;
    o.x = pack2(v[0] * sc, v[1] * sc);
    o.y = pack2(v[2] * sc, v[3] * sc);
    o.z = pack2(v[4] * sc, v[5] * sc);
    o.w = pack2(v[6] * sc, v[7] * sc);
    *(uint4*)(Y + rowg * 64 + fb) = o;
}

// ---------------- FUSED SpMM + combine (layers 1/2), fp8 gather, Y IN-PLACE ----------------
// One wave per node pair. Gather: full-wave contiguous 512B per edge from
// the fp8 snapshot G. Epilogue is register-STREAMED: weight fragments are
// reloaded per output tile (WT is L1/L2-resident) inside a #pragma unroll 1
// loop so only one tile's fragments are live at a time -> peak VGPR stays
// low and the concurrency-bound gather gets its waves back.
// In-place safety: all bf16 reads of Y (p-path, epilogue) touch only this
// wave's 16 rows and precede this wave's writes in program order.
__global__ __launch_bounds__(256) void fused_spmm_f8_k(u16* __restrict__ Y,
                                                       const u8* __restrict__ G,
                                                       const int* __restrict__ row_ptr,
                                                       const int* __restrict__ col,
                                                       const u16* __restrict__ WdT,
                                                       const u16* __restrict__ WpT,
                                                       const float* __restrict__ bd,
                                                       const float* __restrict__ bp) {
    __shared__ u16 lds_t[4 * 16 * 72];
    int lane = threadIdx.x & 63;
    u16* L = lds_t + (threadIdx.x >> 6) * (16 * 72);
    int m = lane & 15, q = lane >> 4;
    const uint2* G2 = (const uint2*)G;

    int wid = (blockIdx.x * 256 + threadIdx.x) >> 6;
    if (wid >= NN / 2) return;
    int pb = wid;

    // ---- gather phase: minimal live registers ----
#pragma unroll
    for (int p = 0; p < 2; p++) {
        int node = pb * 2 + p;
        int start = row_ptr[node], end = row_ptr[node + 1];
        float a[8] = {0.f, 0.f, 0.f, 0.f, 0.f, 0.f, 0.f, 0.f};
        int j = start;
        for (; j + 16 <= end; j += 16) {
            uint2 t[16];
#pragma unroll
            for (int u = 0; u < 16; u++) t[u] = G2[(size_t)col[j + u] * 64 + lane];
#pragma unroll
            for (int u = 0; u < 16; u++) accf8(a, t[u]);
        }
        for (; j + 4 <= end; j += 4) {
            uint2 t[4];
#pragma unroll
            for (int u = 0; u < 4; u++) t[u] = G2[(size_t)col[j + u] * 64 + lane];
#pragma unroll
            for (int u = 0; u < 4; u++) accf8(a, t[u]);
        }
        for (; j < end; j++) {
            uint2 t0 = G2[(size_t)col[j] * 64 + lane];
            accf8(a, t0);
        }
        uint4 o;
        o.x = pack2(a[0], a[1]);
        o.y = pack2(a[2], a[3]);
        o.z = pack2(a[4], a[5]);
        o.w = pack2(a[6], a[7]);
        *(uint4*)(L + (size_t)(p * 8 + (lane >> 3)) * 72 + (lane & 7) * 8) = o;
    }
    __builtin_amdgcn_sched_barrier(0);

    // ---- epilogue: streamed over the 4 output tiles ----
    short8 ay0 = ld_frag(L + m * 72 + q * 8);
    short8 ay1 = ld_frag(L + m * 72 + 32 + q * 8);
    const u16* xr = Y + ((size_t)(pb * 16 + m)) * 64 + q * 8;
    short8 ax0 = ld_frag(xr), ax1 = ld_frag(xr + 32);
    float v[4][4], sq[4];
#pragma unroll
    for (int r = 0; r < 4; r++) sq[r] = 0.f;
#pragma unroll 1
    for (int t = 0; t < 4; t++) {
        int off = (t * 16 + m) * 64 + q * 8;
        short8 bd0 = ld_frag(WdT + off), bd1 = ld_frag(WdT + off + 32);
        short8 bp0 = ld_frag(WpT + off), bp1 = ld_frag(WpT + off + 32);
        f32x4 ad = (f32x4){0.f, 0.f, 0.f, 0.f};
        f32x4 ap = (f32x4){0.f, 0.f, 0.f, 0.f};
        ad = __builtin_amdgcn_mfma_f32_16x16x32_bf16(ay0, bd0, ad, 0, 0, 0);
        ad = __builtin_amdgcn_mfma_f32_16x16x32_bf16(ay1, bd1, ad, 0, 0, 0);
        ap = __builtin_amdgcn_mfma_f32_16x16x32_bf16(ax0, bp0, ap, 0, 0, 0);
        ap = __builtin_amdgcn_mfma_f32_16x16x32_bf16(ax1, bp1, ap, 0, 0, 0);
        float bdv = bd[t * 16 + m], bpv = bp[t * 16 + m];
#pragma unroll
        for (int r = 0; r < 4; r++) {
            float val = ap[r] + bpv + lrelu(ad[r] + bdv);
            v[t][r] = val;
            sq[r] += val * val;
        }
    }
#pragma unroll
    for (int r = 0; r < 4; r++) {
#pragma unroll
        for (int mm = 1; mm < 16; mm <<= 1) sq[r] += __shfl_xor(sq[r], mm, 64);
        float sc = rsqrtf(fmaxf(sq[r], 1e-12f));
        u16* orow = Y + ((size_t)(pb * 16 + q * 4 + r)) * 64 + m;
#pragma unroll
        for (int t = 0; t < 4; t++) orow[t * 16] = (u16)f2b(v[t][r] * sc);
    }
}

// ---------------- pooling: hierarchical + atomics ----------------
__global__ __launch_bounds__(256) void pool2_k(const u16* __restrict__ X,
                                               const int* __restrict__ graph_ids,
                                               float* __restrict__ pooled) {
    int chunk = (NN + gridDim.x - 1) / gridDim.x;
    int n0 = blockIdx.x * chunk;
    int n1 = min(n0 + chunk, NN);
    if (n0 >= n1) return;
    int f = threadIdx.x & 63;
    int c0 = threadIdx.x >> 6;          // 0..3 -> configs c0, c0+4
    float a0 = 0.f, a1 = 0.f;
    int cur = graph_ids[n0];
    for (int n = n0; n < n1; n++) {
        int g = graph_ids[n];
        if (g != cur) {
            atomicAdd(&pooled[(size_t)(cur * 8 + c0) * 64 + f], a0);
            atomicAdd(&pooled[(size_t)(cur * 8 + c0 + 4) * 64 + f], a1);
            a0 = 0.f; a1 = 0.f; cur = g;
        }
        a0 += b2f(X[((size_t)n * 8 + c0) * 64 + f]);
        a1 += b2f(X[((size_t)n * 8 + c0 + 4) * 64 + f]);
    }
    atomicAdd(&pooled[(size_t)(cur * 8 + c0) * 64 + f], a0);
    atomicAdd(&pooled[(size_t)(cur * 8 + c0 + 4) * 64 + f], a1);
}

// ---------------- final MLP over 128 (b,c) rows ----------------
__global__ __launch_bounds__(256) void mlp_k(const float* __restrict__ pooled,
                                             const float* __restrict__ W0, const float* __restrict__ b0,
                                             const float* __restrict__ W1, const float* __restrict__ b1,
                                             const float* __restrict__ W2, const float* __restrict__ b2,
                                             float* __restrict__ out) {
    int lane = threadIdx.x & 63;
    int row = blockIdx.x * 4 + (threadIdx.x >> 6);
    if (row >= BB * CC) return;
    float b0l = b0[lane], b1l = b1[lane], w2l = W2[lane], b2s = b2[0];
    float p = pooled[(size_t)row * 64 + lane];
    float a = 0.f;
    for (int k = 0; k < 64; k++) a = fmaf(rdlane(p, k), W0[k * 64 + lane], a);
    float h0 = lrelu(a + b0l);
    float a1 = 0.f;
    for (int k = 0; k < 64; k++) a1 = fmaf(rdlane(h0, k), W1[k * 64 + lane], a1);
    float h1 = lrelu(a1 + b1l);
    float v = wave_sum64(h1 * w2l);
    if (lane == 0) out[row] = v + b2s;
}

extern "C" void kernel_launch(void* const* d_in, const int* in_sizes, int n_in,
                              void* d_out, int out_size, void* d_ws, size_t ws_size,
                              hipStream_t stream) {
    const float* node_feats   = (const float*)d_in[0];
    const float* config_feats = (const float*)d_in[1];
    const int*   op_ids       = (const int*)d_in[2];
    const int*   src          = (const int*)d_in[3];
    const int*   dst          = (const int*)d_in[4];
    const int*   graph_ids    = (const int*)d_in[5];
    const float* op_emb       = (const float*)d_in[6];
    const float* W_d0 = (const float*)d_in[7],  *b_d0 = (const float*)d_in[8];
    const float* W_p0 = (const float*)d_in[9],  *b_p0 = (const float*)d_in[10];
    const float* W_d1 = (const float*)d_in[11], *b_d1 = (const float*)d_in[12];
    const float* W_p1 = (const float*)d_in[13], *b_p1 = (const float*)d_in[14];
    const float* W_d2 = (const float*)d_in[15], *b_d2 = (const float*)d_in[16];
    const float* W_p2 = (const float*)d_in[17], *b_p2 = (const float*)d_in[18];
    const float* W_m0 = (const float*)d_in[19], *b_m0 = (const float*)d_in[20];
    const float* W_m1 = (const float*)d_in[21], *b_m1 = (const float*)d_in[22];
    const float* W_m2 = (const float*)d_in[23], *b_m2 = (const float*)d_in[24];
    float* out = (float*)d_out;

    // workspace layout (~193.5 MB total)
    char* ws = (char*)d_ws;
    size_t off = 0;
    u16* Y       = (u16*)(ws + off); off += (size_t)NROWS * 64 * 2;   // 102.4 MB
    u8*  G       = (u8*)(ws + off);  off += (size_t)NROWS * 64;       // 51.2 MB
    int* col     = (int*)(ws + off);   off += (size_t)2 * EE * 4;     // 12.8 MB
    int* row_ptr = (int*)(ws + off);   off += 400128;                 // N+1 padded
    u16* WT      = (u16*)(ws + off);   off += (4 * 4096 + 2 * 10240) * 2;
    float* pooled = (float*)(ws + off); off += BB * CC * 64 * 4;
    u16* nf_d    = (u16*)(ws + off); off += (size_t)NN * 64 * 2;      // 12.8 MB
    u16* nf_p    = (u16*)(ws + off); off += (size_t)NN * 64 * 2;      // 12.8 MB
    float* op_d  = (float*)(ws + off); off += 120 * 64 * 4;
    float* op_p  = (float*)(ws + off); off += 120 * 64 * 4;
    int* deg     = (int*)(ws + off);   off += 400128;
    int* cursor  = (int*)(ws + off);   off += 400128;
    int* bsum    = (int*)(ws + off);   off += 512;
    (void)ws_size; (void)in_sizes; (void)n_in; (void)out_size;

    const int NB = (NN + 1023) / 1024;   // 98 scan blocks
    const int NCONV = (NROWS * 64 / 8 + 255) / 256;  // 25000 blocks

    // ---- CSR build + weight prep ----
    hipMemsetAsync(deg, 0, (size_t)NN * 4, stream);
    hipMemsetAsync(pooled, 0, (size_t)BB * CC * 64 * 4, stream);
    deg_count_k<<<(2 * EE) / 256, 256, 0, stream>>>(src, dst, deg);
    prep_w_k<<<144, 256, 0, stream>>>(W_d1, W_p1, W_d2, W_p2,
                                      W_d0 + 64 * 64, W_p0 + 64 * 64, WT);
    scan1_k<<<NB, 1024, 0, stream>>>(deg, row_ptr, bsum, NN);
    scan2_k<<<1, 1, 0, stream>>>(bsum, NB);
    scan3_k<<<NB, 1024, 0, stream>>>(row_ptr, cursor, bsum, NN, NB);
    // chunked placement: 8 passes, each confining col writes to ~1.6MB
    {
        const int NCHUNK = 8;
        const int CSZ = (NN + NCHUNK - 1) / NCHUNK;   // 12500
        for (int c = 0; c < NCHUNK; c++) {
            int c0 = c * CSZ;
            int c1 = min(c0 + CSZ, NN);
            place_k<<<(2 * EE) / 256, 256, 0, stream>>>(src, dst, cursor, col, c0, c1);
        }
    }

    // ---- input projections: G = fp8 d-projection, Y = bf16 p-projection ----
    op_dp_k<<<30, 256, 0, stream>>>(op_emb, W_d0, W_p0, op_d, op_p);
    nf_mfma_k<<<512, 256, 0, stream>>>(node_feats, WT + 16384, WT + 16384 + 10240, nf_d, nf_p);
    hd0_dual_k<<<2048, 256, 0, stream>>>(G, Y, config_feats, op_ids, nf_d, nf_p,
                                         op_d, op_p, W_d0 + 204 * 64, W_p0 + 204 * 64);

    // ---- layer 0: gather G, combine in-place on Y ----
    fused_l0_f8_k<<<NN / 4, 256, 0, stream>>>(G, Y, row_ptr, col, b_d0, b_p0);
    // ---- layer 1: snapshot Y->G, fused SpMM+combine in-place on Y ----
    conv_fp8_k<<<NCONV, 256, 0, stream>>>(Y, (uint2*)G);
    fused_spmm_f8_k<<<12500, 256, 0, stream>>>(Y, G, row_ptr, col,
                                               WT, WT + 4096, b_d1, b_p1);
    // ---- layer 2: snapshot Y->G, fused SpMM+combine in-place on Y ----
    conv_fp8_k<<<NCONV, 256, 0, stream>>>(Y, (uint2*)G);
    fused_spmm_f8_k<<<12500, 256, 0, stream>>>(Y, G, row_ptr, col,
                                               WT + 8192, WT + 12288, b_d2, b_p2);

    // ---- pooling + MLP ----
    pool2_k<<<2048, 256, 0, stream>>>(Y, graph_ids, pooled);
    mlp_k<<<32, 256, 0, stream>>>(pooled, W_m0, b_m0, W_m1, b_m1, W_m2, b_m2, out);
}

// Round 11
// 1519.883 us; speedup vs baseline: 1.4961x; 1.0106x over previous
//
#include <hip/hip_runtime.h>
#include <hip/hip_bf16.h>

// Problem constants (match reference)
#define NN 100000
#define EE 1600000
#define CC 8
#define HH 64
#define NF 140
#define CF 18
#define BB 16
#define NROWS (NN * CC)          // 800000 rows of [64]
#define ALPHA 0.2f

// R19 == R18 resubmitted (prior round died to a container-acquisition
// failure: no timing block, no pytest traceback -> infra, not kernel).
// R18: setup-phase consolidation on top of R17 (1536us).
// R17 confirmed: fp8 gather + low-VGPR streamed epilogue puts all three
// gather kernels at the ~7.5 TB/s vector-miss-path ceiling (spmm 274us,
// l0 ~250us). Core kernels UNCHANGED. The remaining ~630us is setup:
// (a) place 8->4 passes (write regions 3.2MB still L2-clean, read traffic
// halved); (b) scan2 1-thread serial chase (~20us) -> 128-thread shuffle
// scan; (c) deg_count+prep_w+op_dp fused into one block-range kernel;
// (d) conv_fp8 16 elems/thread.
// KEPT: fp8 snapshot G + single in-place bf16 Y, hd0 direct-fp8 emit,
// chunked place. Footprint ~193MB.

typedef unsigned short u16;
typedef unsigned int u32;
typedef unsigned char u8;
typedef __attribute__((ext_vector_type(8))) short short8;   // 8 bf16 (4 VGPRs)
typedef __attribute__((ext_vector_type(4))) float f32x4;    // MFMA accum
typedef __attribute__((ext_vector_type(4))) float fv4;
typedef __attribute__((ext_vector_type(2))) float f32x2;

__device__ __forceinline__ float rdlane(float v, int l) {
    return __int_as_float(__builtin_amdgcn_readlane(__float_as_int(v), l));
}
__device__ __forceinline__ float lrelu(float x) { return x > 0.f ? x : ALPHA * x; }
__device__ __forceinline__ float wave_sum64(float v) {
#pragma unroll
    for (int m = 1; m < 64; m <<= 1) v += __shfl_xor(v, m, 64);
    return v;
}
__device__ __forceinline__ float b2f(u16 u) { return __uint_as_float(((u32)u) << 16); }
__device__ __forceinline__ u32 f2b(float f) {
    u32 u = __float_as_uint(f);
    return (u + 0x7fffu + ((u >> 16) & 1u)) >> 16;
}
__device__ __forceinline__ u32 pack2(float lo, float hi) {
    return f2b(lo) | (f2b(hi) << 16);
}
__device__ __forceinline__ short8 ld_frag(const u16* p) {
    union { uint4 u; short8 s; } c;
    c.u = *(const uint4*)p;
    return c.s;
}

// ---------------- fp8 e4m3 helpers ----------------
#if __has_builtin(__builtin_amdgcn_cvt_pk_f32_fp8) && __has_builtin(__builtin_amdgcn_cvt_pk_fp8_f32)
#define HAS_HW_FP8 1
#else
#define HAS_HW_FP8 0
#endif

__device__ __forceinline__ float dec8_sw(u32 b) {
    u32 u = ((b & 0x80u) << 24) | ((b & 0x7fu) << 20);
    return __uint_as_float(u) * 0x1.0p+120f;
}
__device__ __forceinline__ u32 enc8_sw(float f) {
    f = fminf(fmaxf(f, -448.f), 448.f);
    u32 u = __float_as_uint(f * 0x1.0p-120f);
    u32 r = u + 0x7ffffu + ((u >> 20) & 1u);
    return ((r >> 24) & 0x80u) | ((r >> 20) & 0x7fu);
}
__device__ __forceinline__ u32 pk4_fp8(float a, float b, float c, float d) {
#if HAS_HW_FP8
    u32 w = 0;
    w = __builtin_amdgcn_cvt_pk_fp8_f32(a, b, w, false);
    w = __builtin_amdgcn_cvt_pk_fp8_f32(c, d, w, true);
    return w;
#else
    return enc8_sw(a) | (enc8_sw(b) << 8) | (enc8_sw(c) << 16) | (enc8_sw(d) << 24);
#endif
}
// accumulate 8 fp8 values (one uint2) into a[8]
__device__ __forceinline__ void accf8(float* a, uint2 t) {
#if HAS_HW_FP8
    f32x2 d;
    d = __builtin_amdgcn_cvt_pk_f32_fp8(t.x, false); a[0] += d.x; a[1] += d.y;
    d = __builtin_amdgcn_cvt_pk_f32_fp8(t.x, true);  a[2] += d.x; a[3] += d.y;
    d = __builtin_amdgcn_cvt_pk_f32_fp8(t.y, false); a[4] += d.x; a[5] += d.y;
    d = __builtin_amdgcn_cvt_pk_f32_fp8(t.y, true);  a[6] += d.x; a[7] += d.y;
#else
    u32 w[2] = {t.x, t.y};
#pragma unroll
    for (int q = 0; q < 2; q++) {
        a[q*4+0] += dec8_sw(w[q] & 0xffu);
        a[q*4+1] += dec8_sw((w[q] >> 8) & 0xffu);
        a[q*4+2] += dec8_sw((w[q] >> 16) & 0xffu);
        a[q*4+3] += dec8_sw((w[q] >> 24) & 0xffu);
    }
#endif
}

// ---------------- fused setup: deg_count + prep_w + op_dp ----------------
// Independent pieces dispatched by block range: [0,12500) deg_count,
// [12500,12644) prep_w, [12644,12674) op_dp.
#define SETUP_DEG_BLK 12500
#define SETUP_PW_BLK  144
#define SETUP_OP_BLK  30
__global__ __launch_bounds__(256) void setup_k(const int* __restrict__ src,
                                               const int* __restrict__ dst,
                                               int* __restrict__ deg,
                                               const float* __restrict__ Wd1, const float* __restrict__ Wp1,
                                               const float* __restrict__ Wd2, const float* __restrict__ Wp2,
                                               const float* __restrict__ Wd0nf, const float* __restrict__ Wp0nf,
                                               u16* __restrict__ WT,
                                               const float* __restrict__ op_emb,
                                               const float* __restrict__ Wd_top,
                                               const float* __restrict__ Wp_top,
                                               float* __restrict__ op_d,
                                               float* __restrict__ op_p) {
    int b = blockIdx.x;
    if (b < SETUP_DEG_BLK) {
        int e = b * 256 + threadIdx.x;
        if (e < EE) atomicAdd(&deg[dst[e]], 1);
        else if (e < 2 * EE) atomicAdd(&deg[src[e - EE]], 1);
        return;
    }
    b -= SETUP_DEG_BLK;
    if (b < SETUP_PW_BLK) {
        int i = b * 256 + threadIdx.x;
        if (i < 4 * 4096) {
            int w = i >> 12, idx = i & 4095;
            int n = idx >> 6, k = idx & 63;
            const float* W = (w == 0) ? Wd1 : (w == 1) ? Wp1 : (w == 2) ? Wd2 : Wp2;
            WT[w * 4096 + n * 64 + k] = (u16)f2b(W[k * 64 + n]);
        } else {
            int j = i - 4 * 4096;
            if (j < 2 * 64 * 160) {
                int w = j / 10240, idx = j % 10240;
                int n = idx / 160, k = idx % 160;
                const float* W = w ? Wp0nf : Wd0nf;
                WT[16384 + w * 10240 + n * 160 + k] = (k < 140) ? (u16)f2b(W[k * 64 + n]) : (u16)0;
            }
        }
        return;
    }
    b -= SETUP_PW_BLK;
    {
        int lane = threadIdx.x & 63;
        int wid = (b * 256 + threadIdx.x) >> 6;
        if (wid >= 120) return;
        float v = op_emb[wid * 64 + lane];
        float ad = 0.f, ap = 0.f;
        for (int k = 0; k < 64; k++) {
            float s = rdlane(v, k);
            ad = fmaf(s, Wd_top[k * 64 + lane], ad);
            ap = fmaf(s, Wp_top[k * 64 + lane], ap);
        }
        op_d[wid * 64 + lane] = ad;
        op_p[wid * 64 + lane] = ap;
    }
}

__global__ __launch_bounds__(1024) void scan1_k(const int* __restrict__ deg,
                                                int* __restrict__ row_ptr,
                                                int* __restrict__ bsum, int n) {
    __shared__ int lds[17];
    int i = blockIdx.x * 1024 + threadIdx.x;
    int lane = threadIdx.x & 63, wv = threadIdx.x >> 6;
    int val = (i < n) ? deg[i] : 0;
    int v = val;
#pragma unroll
    for (int d = 1; d < 64; d <<= 1) {
        int t = __shfl_up(v, d, 64);
        if (lane >= d) v += t;
    }
    if (lane == 63) lds[wv] = v;
    __syncthreads();
    if (threadIdx.x == 0) {
        int run = 0;
#pragma unroll
        for (int k = 0; k < 16; k++) { int t = lds[k]; lds[k] = run; run += t; }
        lds[16] = run;
    }
    __syncthreads();
    if (i < n) row_ptr[i] = v - val + lds[wv];
    if (threadIdx.x == 1023) bsum[blockIdx.x] = lds[16];
}

// parallel block-sum scan (was 1-thread serial chase ~20us)
__global__ __launch_bounds__(128) void scan2_k(int* __restrict__ bsum, int nb) {
    __shared__ int wsum[2];
    int tid = threadIdx.x;
    int lane = tid & 63, wv = tid >> 6;
    int val = (tid < nb) ? bsum[tid] : 0;
    int v = val;
#pragma unroll
    for (int d = 1; d < 64; d <<= 1) {
        int t = __shfl_up(v, d, 64);
        if (lane >= d) v += t;
    }
    if (lane == 63) wsum[wv] = v;
    __syncthreads();
    int incl = v + ((wv == 1) ? wsum[0] : 0);
    if (tid < nb) bsum[tid] = incl - val;     // exclusive prefix
    if (tid == 127) bsum[nb] = incl;          // total
}

__global__ __launch_bounds__(1024) void scan3_k(int* __restrict__ row_ptr,
                                                int* __restrict__ cursor,
                                                const int* __restrict__ bsum,
                                                int n, int nb) {
    int i = blockIdx.x * 1024 + threadIdx.x;
    if (i < n) {
        int v = row_ptr[i] + bsum[blockIdx.x];
        row_ptr[i] = v;
        cursor[i] = v;
    }
    if (i == 0) row_ptr[n] = bsum[nb];
}

// Chunked placement (R11, now 4 passes): only edges whose dst node is in [c0,c1).
__global__ __launch_bounds__(256) void place_k(const int* __restrict__ src,
                                               const int* __restrict__ dst,
                                               int* __restrict__ cursor,
                                               int* __restrict__ col,
                                               int c0, int c1) {
    int e = blockIdx.x * 256 + threadIdx.x;
    int node, other;
    if (e < EE) { node = dst[e]; other = src[e]; }
    else if (e < 2 * EE) { node = src[e - EE]; other = dst[e - EE]; }
    else return;
    if (node < c0 || node >= c1) return;
    int pos = atomicAdd(&cursor[node], 1);
    col[pos] = other;
}

// ---------------- nf projections via MFMA ----------------
__global__ __launch_bounds__(256) void nf_mfma_k(const float* __restrict__ nf,
                                                 const u16* __restrict__ WdT0,
                                                 const u16* __restrict__ WpT0,
                                                 u16* __restrict__ nf_d,
                                                 u16* __restrict__ nf_p) {
    int lane = threadIdx.x & 63;
    int m = lane & 15, q = lane >> 4;
    int wid = (blockIdx.x * 256 + threadIdx.x) >> 6;
    int nw = (gridDim.x * 256) >> 6;
    for (int rb = wid; rb < NN / 16; rb += nw) {
        int node0 = rb * 16;
        const float* row = nf + (size_t)(node0 + m) * 140;
        short8 af[5];
#pragma unroll
        for (int s = 0; s < 5; s++) {
            int k0 = s * 32 + q * 8;
            float f[8];
            if (s < 4) {
                fv4 lo = __builtin_nontemporal_load((const fv4*)(row + k0));
                fv4 hi = __builtin_nontemporal_load((const fv4*)(row + k0 + 4));
                f[0]=lo.x; f[1]=lo.y; f[2]=lo.z; f[3]=lo.w;
                f[4]=hi.x; f[5]=hi.y; f[6]=hi.z; f[7]=hi.w;
            } else {
#pragma unroll
                for (int j = 0; j < 8; j++) f[j] = 0.f;
                if (q == 0) {
                    fv4 lo = __builtin_nontemporal_load((const fv4*)(row + 128));
                    fv4 hi = __builtin_nontemporal_load((const fv4*)(row + 132));
                    f[0]=lo.x; f[1]=lo.y; f[2]=lo.z; f[3]=lo.w;
                    f[4]=hi.x; f[5]=hi.y; f[6]=hi.z; f[7]=hi.w;
                } else if (q == 1) {
                    fv4 lo = __builtin_nontemporal_load((const fv4*)(row + 136));
                    f[0]=lo.x; f[1]=lo.y; f[2]=lo.z; f[3]=lo.w;
                }
            }
            short8 t;
#pragma unroll
            for (int j = 0; j < 8; j++) t[j] = (short)f2b(f[j]);
            af[s] = t;
        }
        f32x4 ad[4], ap[4];
#pragma unroll
        for (int t = 0; t < 4; t++) {
            ad[t] = (f32x4){0.f, 0.f, 0.f, 0.f};
            ap[t] = (f32x4){0.f, 0.f, 0.f, 0.f};
        }
#pragma unroll
        for (int s = 0; s < 5; s++) {
#pragma unroll
            for (int t = 0; t < 4; t++) {
                int boff = (t * 16 + m) * 160 + s * 32 + q * 8;
                short8 bdw = ld_frag(WdT0 + boff);
                short8 bpw = ld_frag(WpT0 + boff);
                ad[t] = __builtin_amdgcn_mfma_f32_16x16x32_bf16(af[s], bdw, ad[t], 0, 0, 0);
                ap[t] = __builtin_amdgcn_mfma_f32_16x16x32_bf16(af[s], bpw, ap[t], 0, 0, 0);
            }
        }
#pragma unroll
        for (int r = 0; r < 4; r++) {
            size_t nrow = (size_t)(node0 + q * 4 + r);
#pragma unroll
            for (int t = 0; t < 4; t++) {
                nf_d[nrow * 64 + t * 16 + m] = (u16)f2b(ad[t][r]);
                nf_p[nrow * 64 + t * 16 + m] = (u16)f2b(ap[t][r]);
            }
        }
    }
}

// hd0 v3: G[row] = fp8(op_d + nf_d + cf@WdBot) ; Y[row] = bf16(op_p + nf_p + cf@WpBot)
__global__ __launch_bounds__(256) void hd0_dual_k(u8* __restrict__ G,
                                                  u16* __restrict__ Y,
                                                  const float* __restrict__ cf,
                                                  const int* __restrict__ op_ids,
                                                  const u16* __restrict__ nf_d,
                                                  const u16* __restrict__ nf_p,
                                                  const float* __restrict__ op_d,
                                                  const float* __restrict__ op_p,
                                                  const float* __restrict__ WdBot,
                                                  const float* __restrict__ WpBot) {
    int lane = threadIdx.x & 63;
    float wbd[18], wbp[18];
#pragma unroll
    for (int k = 0; k < 18; k++) { wbd[k] = WdBot[k * 64 + lane]; wbp[k] = WpBot[k * 64 + lane]; }
    int wid = (blockIdx.x * 256 + threadIdx.x) >> 6;
    int nw = (gridDim.x * 256) >> 6;
    for (int row = wid; row < NROWS; row += nw) {
        int n = row >> 3;
        float cfv = (lane < 18) ? __builtin_nontemporal_load(cf + (size_t)row * 18 + lane) : 0.f;
        int op = op_ids[n];
        float accd = op_d[op * 64 + lane] + b2f(nf_d[(size_t)n * 64 + lane]);
        float accp = op_p[op * 64 + lane] + b2f(nf_p[(size_t)n * 64 + lane]);
#pragma unroll
        for (int k = 0; k < 18; k++) {
            float s = rdlane(cfv, k);
            accd = fmaf(s, wbd[k], accd);
            accp = fmaf(s, wbp[k], accp);
        }
        // pack 4 lanes' accd into one fp8 u32 (lane&3==0 writes)
        float f1 = __shfl_down(accd, 1, 64);
        float f2 = __shfl_down(accd, 2, 64);
        float f3 = __shfl_down(accd, 3, 64);
        if ((lane & 3) == 0)
            ((u32*)G)[(size_t)row * 16 + (lane >> 2)] = pk4_fp8(accd, f1, f2, f3);
        Y[(size_t)row * 64 + lane] = (u16)f2b(accp);
    }
}

// ---------------- bf16 -> fp8 mirror conversion (16 elems/thread) ----------------
__global__ __launch_bounds__(256) void conv_fp8_k(const u16* __restrict__ src,
                                                  uint4* __restrict__ dst) {
    int i = blockIdx.x * 256 + threadIdx.x;   // each thread: 16 elems
    if (i >= NROWS * 4) return;               // NROWS*64/16
    short8 v0 = ld_frag(src + (size_t)i * 16);
    short8 v1 = ld_frag(src + (size_t)i * 16 + 8);
    float f[16];
#pragma unroll
    for (int k = 0; k < 8; k++) { f[k] = b2f((u16)v0[k]); f[k + 8] = b2f((u16)v1[k]); }
    uint4 o;
    o.x = pk4_fp8(f[0], f[1], f[2], f[3]);
    o.y = pk4_fp8(f[4], f[5], f[6], f[7]);
    o.z = pk4_fp8(f[8], f[9], f[10], f[11]);
    o.w = pk4_fp8(f[12], f[13], f[14], f[15]);
    dst[i] = o;
}

// ---------------- FUSED layer 0: fp8 gather (full-wave contiguous), Y in-place ----------------
// [UNCHANGED from R17]
__global__ __launch_bounds__(256) void fused_l0_f8_k(const u8* __restrict__ G,
                                                     u16* __restrict__ Y,
                                                     const int* __restrict__ row_ptr,
                                                     const int* __restrict__ col,
                                                     const float* __restrict__ bd,
                                                     const float* __restrict__ bp) {
    int wid = (blockIdx.x * 256 + threadIdx.x) >> 6;
    int lane = threadIdx.x & 63;
    if (wid >= NN) return;
    int r = lane >> 3, fb = (lane & 7) * 8;
    const uint2* G2 = (const uint2*)G;
    int start = row_ptr[wid];
    int end = row_ptr[wid + 1];
    float a[8] = {0.f, 0.f, 0.f, 0.f, 0.f, 0.f, 0.f, 0.f};
    int j = start;
    for (; j + 16 <= end; j += 16) {
        uint2 t[16];
#pragma unroll
        for (int u = 0; u < 16; u++) t[u] = G2[(size_t)col[j + u] * 64 + lane];
#pragma unroll
        for (int u = 0; u < 16; u++) accf8(a, t[u]);
    }
    for (; j + 4 <= end; j += 4) {
        uint2 t[4];
#pragma unroll
        for (int u = 0; u < 4; u++) t[u] = G2[(size_t)col[j + u] * 64 + lane];
#pragma unroll
        for (int u = 0; u < 4; u++) accf8(a, t[u]);
    }
    for (; j < end; j++) {
        uint2 t0 = G2[(size_t)col[j] * 64 + lane];
        accf8(a, t0);
    }
    // epilogue (loads after gather)
    float bdv[8], bpv[8];
#pragma unroll
    for (int jj = 0; jj < 8; jj++) { bdv[jj] = bd[fb + jj]; bpv[jj] = bp[fb + jj]; }
    size_t rowg = (size_t)wid * 8 + r;
    short8 xp = ld_frag(Y + rowg * 64 + fb);
    float v[8], sq = 0.f;
#pragma unroll
    for (int q = 0; q < 8; q++) {
        float val = b2f((u16)xp[q]) + bpv[q] + lrelu(a[q] + bdv[q]);
        v[q] = val;
        sq += val * val;
    }
    sq += __shfl_xor(sq, 1, 64);
    sq += __shfl_xor(sq, 2, 64);
    sq += __shfl_xor(sq, 4, 64);
    float sc = rsqrtf(fmaxf(sq, 1e-12f));
    uint4 o;
    o.x = pack2(v[0] * sc, v[1] * sc);
    o.y = pack2(v[2] * sc, v[3] * sc);
    o.z = pack2(v[4] * sc, v[5] * sc);
    o.w = pack2(v[6] * sc, v[7] * sc);
    *(uint4*)(Y + rowg * 64 + fb) = o;
}

// ---------------- FUSED SpMM + combine (layers 1/2), fp8 gather, Y IN-PLACE ----------------
// [UNCHANGED from R17: VGPR 56 / 40% occ / 274us]
__global__ __launch_bounds__(256) void fused_spmm_f8_k(u16* __restrict__ Y,
                                                       const u8* __restrict__ G,
                                                       const int* __restrict__ row_ptr,
                                                       const int* __restrict__ col,
                                                       const u16* __restrict__ WdT,
                                                       const u16* __restrict__ WpT,
                                                       const float* __restrict__ bd,
                                                       const float* __restrict__ bp) {
    __shared__ u16 lds_t[4 * 16 * 72];
    int lane = threadIdx.x & 63;
    u16* L = lds_t + (threadIdx.x >> 6) * (16 * 72);
    int m = lane & 15, q = lane >> 4;
    const uint2* G2 = (const uint2*)G;

    int wid = (blockIdx.x * 256 + threadIdx.x) >> 6;
    if (wid >= NN / 2) return;
    int pb = wid;

    // ---- gather phase: minimal live registers ----
#pragma unroll
    for (int p = 0; p < 2; p++) {
        int node = pb * 2 + p;
        int start = row_ptr[node], end = row_ptr[node + 1];
        float a[8] = {0.f, 0.f, 0.f, 0.f, 0.f, 0.f, 0.f, 0.f};
        int j = start;
        for (; j + 16 <= end; j += 16) {
            uint2 t[16];
#pragma unroll
            for (int u = 0; u < 16; u++) t[u] = G2[(size_t)col[j + u] * 64 + lane];
#pragma unroll
            for (int u = 0; u < 16; u++) accf8(a, t[u]);
        }
        for (; j + 4 <= end; j += 4) {
            uint2 t[4];
#pragma unroll
            for (int u = 0; u < 4; u++) t[u] = G2[(size_t)col[j + u] * 64 + lane];
#pragma unroll
            for (int u = 0; u < 4; u++) accf8(a, t[u]);
        }
        for (; j < end; j++) {
            uint2 t0 = G2[(size_t)col[j] * 64 + lane];
            accf8(a, t0);
        }
        uint4 o;
        o.x = pack2(a[0], a[1]);
        o.y = pack2(a[2], a[3]);
        o.z = pack2(a[4], a[5]);
        o.w = pack2(a[6], a[7]);
        *(uint4*)(L + (size_t)(p * 8 + (lane >> 3)) * 72 + (lane & 7) * 8) = o;
    }
    __builtin_amdgcn_sched_barrier(0);

    // ---- epilogue: streamed over the 4 output tiles ----
    short8 ay0 = ld_frag(L + m * 72 + q * 8);
    short8 ay1 = ld_frag(L + m * 72 + 32 + q * 8);
    const u16* xr = Y + ((size_t)(pb * 16 + m)) * 64 + q * 8;
    short8 ax0 = ld_frag(xr), ax1 = ld_frag(xr + 32);
    float v[4][4], sq[4];
#pragma unroll
    for (int r = 0; r < 4; r++) sq[r] = 0.f;
#pragma unroll 1
    for (int t = 0; t < 4; t++) {
        int off = (t * 16 + m) * 64 + q * 8;
        short8 bd0 = ld_frag(WdT + off), bd1 = ld_frag(WdT + off + 32);
        short8 bp0 = ld_frag(WpT + off), bp1 = ld_frag(WpT + off + 32);
        f32x4 ad = (f32x4){0.f, 0.f, 0.f, 0.f};
        f32x4 ap = (f32x4){0.f, 0.f, 0.f, 0.f};
        ad = __builtin_amdgcn_mfma_f32_16x16x32_bf16(ay0, bd0, ad, 0, 0, 0);
        ad = __builtin_amdgcn_mfma_f32_16x16x32_bf16(ay1, bd1, ad, 0, 0, 0);
        ap = __builtin_amdgcn_mfma_f32_16x16x32_bf16(ax0, bp0, ap, 0, 0, 0);
        ap = __builtin_amdgcn_mfma_f32_16x16x32_bf16(ax1, bp1, ap, 0, 0, 0);
        float bdv = bd[t * 16 + m], bpv = bp[t * 16 + m];
#pragma unroll
        for (int r = 0; r < 4; r++) {
            float val = ap[r] + bpv + lrelu(ad[r] + bdv);
            v[t][r] = val;
            sq[r] += val * val;
        }
    }
#pragma unroll
    for (int r = 0; r < 4; r++) {
#pragma unroll
        for (int mm = 1; mm < 16; mm <<= 1) sq[r] += __shfl_xor(sq[r], mm, 64);
        float sc = rsqrtf(fmaxf(sq[r], 1e-12f));
        u16* orow = Y + ((size_t)(pb * 16 + q * 4 + r)) * 64 + m;
#pragma unroll
        for (int t = 0; t < 4; t++) orow[t * 16] = (u16)f2b(v[t][r] * sc);
    }
}

// ---------------- pooling: hierarchical + atomics ----------------
__global__ __launch_bounds__(256) void pool2_k(const u16* __restrict__ X,
                                               const int* __restrict__ graph_ids,
                                               float* __restrict__ pooled) {
    int chunk = (NN + gridDim.x - 1) / gridDim.x;
    int n0 = blockIdx.x * chunk;
    int n1 = min(n0 + chunk, NN);
    if (n0 >= n1) return;
    int f = threadIdx.x & 63;
    int c0 = threadIdx.x >> 6;          // 0..3 -> configs c0, c0+4
    float a0 = 0.f, a1 = 0.f;
    int cur = graph_ids[n0];
    for (int n = n0; n < n1; n++) {
        int g = graph_ids[n];
        if (g != cur) {
            atomicAdd(&pooled[(size_t)(cur * 8 + c0) * 64 + f], a0);
            atomicAdd(&pooled[(size_t)(cur * 8 + c0 + 4) * 64 + f], a1);
            a0 = 0.f; a1 = 0.f; cur = g;
        }
        a0 += b2f(X[((size_t)n * 8 + c0) * 64 + f]);
        a1 += b2f(X[((size_t)n * 8 + c0 + 4) * 64 + f]);
    }
    atomicAdd(&pooled[(size_t)(cur * 8 + c0) * 64 + f], a0);
    atomicAdd(&pooled[(size_t)(cur * 8 + c0 + 4) * 64 + f], a1);
}

// ---------------- final MLP over 128 (b,c) rows ----------------
__global__ __launch_bounds__(256) void mlp_k(const float* __restrict__ pooled,
                                             const float* __restrict__ W0, const float* __restrict__ b0,
                                             const float* __restrict__ W1, const float* __restrict__ b1,
                                             const float* __restrict__ W2, const float* __restrict__ b2,
                                             float* __restrict__ out) {
    int lane = threadIdx.x & 63;
    int row = blockIdx.x * 4 + (threadIdx.x >> 6);
    if (row >= BB * CC) return;
    float b0l = b0[lane], b1l = b1[lane], w2l = W2[lane], b2s = b2[0];
    float p = pooled[(size_t)row * 64 + lane];
    float a = 0.f;
    for (int k = 0; k < 64; k++) a = fmaf(rdlane(p, k), W0[k * 64 + lane], a);
    float h0 = lrelu(a + b0l);
    float a1 = 0.f;
    for (int k = 0; k < 64; k++) a1 = fmaf(rdlane(h0, k), W1[k * 64 + lane], a1);
    float h1 = lrelu(a1 + b1l);
    float v = wave_sum64(h1 * w2l);
    if (lane == 0) out[row] = v + b2s;
}

extern "C" void kernel_launch(void* const* d_in, const int* in_sizes, int n_in,
                              void* d_out, int out_size, void* d_ws, size_t ws_size,
                              hipStream_t stream) {
    const float* node_feats   = (const float*)d_in[0];
    const float* config_feats = (const float*)d_in[1];
    const int*   op_ids       = (const int*)d_in[2];
    const int*   src          = (const int*)d_in[3];
    const int*   dst          = (const int*)d_in[4];
    const int*   graph_ids    = (const int*)d_in[5];
    const float* op_emb       = (const float*)d_in[6];
    const float* W_d0 = (const float*)d_in[7],  *b_d0 = (const float*)d_in[8];
    const float* W_p0 = (const float*)d_in[9],  *b_p0 = (const float*)d_in[10];
    const float* W_d1 = (const float*)d_in[11], *b_d1 = (const float*)d_in[12];
    const float* W_p1 = (const float*)d_in[13], *b_p1 = (const float*)d_in[14];
    const float* W_d2 = (const float*)d_in[15], *b_d2 = (const float*)d_in[16];
    const float* W_p2 = (const float*)d_in[17], *b_p2 = (const float*)d_in[18];
    const float* W_m0 = (const float*)d_in[19], *b_m0 = (const float*)d_in[20];
    const float* W_m1 = (const float*)d_in[21], *b_m1 = (const float*)d_in[22];
    const float* W_m2 = (const float*)d_in[23], *b_m2 = (const float*)d_in[24];
    float* out = (float*)d_out;

    // workspace layout (~193.5 MB total)
    char* ws = (char*)d_ws;
    size_t off = 0;
    u16* Y       = (u16*)(ws + off); off += (size_t)NROWS * 64 * 2;   // 102.4 MB
    u8*  G       = (u8*)(ws + off);  off += (size_t)NROWS * 64;       // 51.2 MB
    int* col     = (int*)(ws + off);   off += (size_t)2 * EE * 4;     // 12.8 MB
    int* row_ptr = (int*)(ws + off);   off += 400128;                 // N+1 padded
    u16* WT      = (u16*)(ws + off);   off += (4 * 4096 + 2 * 10240) * 2;
    float* pooled = (float*)(ws + off); off += BB * CC * 64 * 4;
    u16* nf_d    = (u16*)(ws + off); off += (size_t)NN * 64 * 2;      // 12.8 MB
    u16* nf_p    = (u16*)(ws + off); off += (size_t)NN * 64 * 2;      // 12.8 MB
    float* op_d  = (float*)(ws + off); off += 120 * 64 * 4;
    float* op_p  = (float*)(ws + off); off += 120 * 64 * 4;
    int* deg     = (int*)(ws + off);   off += 400128;
    int* cursor  = (int*)(ws + off);   off += 400128;
    int* bsum    = (int*)(ws + off);   off += 512;
    (void)ws_size; (void)in_sizes; (void)n_in; (void)out_size;

    const int NB = (NN + 1023) / 1024;   // 98 scan blocks
    const int NCONV = NROWS * 4 / 256;   // 12500 blocks (16 elems/thread)

    // ---- fused setup: deg_count + prep_w + op_dp ----
    hipMemsetAsync(deg, 0, (size_t)NN * 4, stream);
    hipMemsetAsync(pooled, 0, (size_t)BB * CC * 64 * 4, stream);
    setup_k<<<SETUP_DEG_BLK + SETUP_PW_BLK + SETUP_OP_BLK, 256, 0, stream>>>(
        src, dst, deg,
        W_d1, W_p1, W_d2, W_p2, W_d0 + 64 * 64, W_p0 + 64 * 64, WT,
        op_emb, W_d0, W_p0, op_d, op_p);
    scan1_k<<<NB, 1024, 0, stream>>>(deg, row_ptr, bsum, NN);
    scan2_k<<<1, 128, 0, stream>>>(bsum, NB);
    scan3_k<<<NB, 1024, 0, stream>>>(row_ptr, cursor, bsum, NN, NB);
    // chunked placement: 4 passes, write regions 3.2MB (L2-clean), reads halved
    {
        const int NCHUNK = 4;
        const int CSZ = (NN + NCHUNK - 1) / NCHUNK;   // 25000
        for (int c = 0; c < NCHUNK; c++) {
            int c0 = c * CSZ;
            int c1 = min(c0 + CSZ, NN);
            place_k<<<(2 * EE) / 256, 256, 0, stream>>>(src, dst, cursor, col, c0, c1);
        }
    }

    // ---- input projections: G = fp8 d-projection, Y = bf16 p-projection ----
    nf_mfma_k<<<512, 256, 0, stream>>>(node_feats, WT + 16384, WT + 16384 + 10240, nf_d, nf_p);
    hd0_dual_k<<<2048, 256, 0, stream>>>(G, Y, config_feats, op_ids, nf_d, nf_p,
                                         op_d, op_p, W_d0 + 204 * 64, W_p0 + 204 * 64);

    // ---- layer 0: gather G, combine in-place on Y ----
    fused_l0_f8_k<<<NN / 4, 256, 0, stream>>>(G, Y, row_ptr, col, b_d0, b_p0);
    // ---- layer 1: snapshot Y->G, fused SpMM+combine in-place on Y ----
    conv_fp8_k<<<NCONV, 256, 0, stream>>>(Y, (uint4*)G);
    fused_spmm_f8_k<<<12500, 256, 0, stream>>>(Y, G, row_ptr, col,
                                               WT, WT + 4096, b_d1, b_p1);
    // ---- layer 2: snapshot Y->G, fused SpMM+combine in-place on Y ----
    conv_fp8_k<<<NCONV, 256, 0, stream>>>(Y, (uint4*)G);
    fused_spmm_f8_k<<<12500, 256, 0, stream>>>(Y, G, row_ptr, col,
                                               WT + 8192, WT + 12288, b_d2, b_p2);

    // ---- pooling + MLP ----
    pool2_k<<<2048, 256, 0, stream>>>(Y, graph_ids, pooled);
    mlp_k<<<32, 256, 0, stream>>>(pooled, W_m0, b_m0, W_m1, b_m1, W_m2, b_m2, out);
}